// Round 1
// 761.062 us; speedup vs baseline: 1.0184x; 1.0184x over previous
//
#include <hip/hip_runtime.h>
#include <math.h>

#define B_   32
#define K_   2048
#define C_   256
#define P_   256
#define S_   16
#define OUTC 119

// output offsets (floats)
#define OFF0 0        // obj        (B,P,2)
#define OFF1 16384    // center     (B,P,3)
#define OFF2 40960    // size_scores(B,P,18)
#define OFF3 188416   // size_res   (B,P,18,3)
#define OFF4 630784   // pred_size  (B,P,3)
#define OFF5 655360   // sem        (B,P,18)
#define OFF6 802816   // corners    (B,P,8,3)
#define OFF7 999424   // sem_logits (B,P,19)
#define OFF8 1155072  // obj_prob   (B,P)
#define OFF9 1163264  // sem_prob   (B,P,18)

typedef _Float16 half8  __attribute__((ext_vector_type(8)));
typedef _Float16 half4h __attribute__((ext_vector_type(4)));
typedef float    f32x4  __attribute__((ext_vector_type(4)));
#define MFMA16 __builtin_amdgcn_mfma_f32_16x16x32_f16

__device__ __forceinline__ float sqdist_rn(float ax, float ay, float az,
                                           float bx, float by, float bz) {
  float dx = __fsub_rn(ax, bx), dy = __fsub_rn(ay, by), dz = __fsub_rn(az, bz);
  return __fadd_rn(__fadd_rn(__fmul_rn(dx, dx), __fmul_rn(dy, dy)),
                   __fmul_rn(dz, dz));
}

// ------------------------------------------- weight split to f16 hi/lo -----
// Fragment-order layout: Wf[tile = ot*nks + ks][lane][8] -> A-frag load is
// one coalesced 1KB wave read. sa l0 padded K 259->288 (9 k-steps).
// Blocks: 0..143 w1, 144..271 w2, 272..399 w3, 400..527 pw1, 528..655 pw2,
// 656: BN scale prep (sa 768 + p-layers 512). pw3 stays f32 (l2 exact).
__global__ __launch_bounds__(64) void wsplit_kernel(
    const float* __restrict__ w1, const float* __restrict__ w2,
    const float* __restrict__ w3, const float* __restrict__ pw1,
    const float* __restrict__ pw2, const float* __restrict__ gma,
    const float* __restrict__ var, const float* __restrict__ pg,
    const float* __restrict__ pv, _Float16* __restrict__ w1h,
    _Float16* __restrict__ w1l, _Float16* __restrict__ w2h,
    _Float16* __restrict__ w2l, _Float16* __restrict__ w3h,
    _Float16* __restrict__ w3l, _Float16* __restrict__ p1h,
    _Float16* __restrict__ p1l, _Float16* __restrict__ p2h,
    _Float16* __restrict__ p2l, float* __restrict__ bns) {
  const int r = blockIdx.x, t = threadIdx.x;
  if (r == 656) {
    for (int u = t; u < 768; u += 64) bns[u] = gma[u] / sqrtf(var[u] + 1e-5f);
    for (int u = t; u < 512; u += 64)
      bns[768 + u] = pg[u] / sqrtf(pv[u] + 1e-5f);
    return;
  }
  const float* src;
  _Float16 *dh, *dl;
  int ot, ks, nks, K;
  if (r < 144) {
    src = w1; dh = w1h; dl = w1l; ot = r / 9; ks = r % 9; nks = 9; K = 259;
  } else if (r < 272) {
    const int rr = r - 144;
    src = w2; dh = w2h; dl = w2l; ot = rr >> 3; ks = rr & 7; nks = 8; K = 256;
  } else if (r < 400) {
    const int rr = r - 272;
    src = w3; dh = w3h; dl = w3l; ot = rr >> 3; ks = rr & 7; nks = 8; K = 256;
  } else if (r < 528) {
    const int rr = r - 400;
    src = pw1; dh = p1h; dl = p1l; ot = rr >> 3; ks = rr & 7; nks = 8; K = 256;
  } else {
    const int rr = r - 528;
    src = pw2; dh = p2h; dl = p2l; ot = rr >> 3; ks = rr & 7; nks = 8; K = 256;
  }
  const int m = t & 15, q = t >> 4;
  const float* row = src + (ot * 16 + m) * K;
  half8 vh, vl;
#pragma unroll
  for (int j = 0; j < 8; j++) {
    const int c = ks * 32 + q * 8 + j;
    const float v = (c < K) ? row[c] : 0.f;
    const _Float16 hi = (_Float16)v;
    vh[j] = hi;
    vl[j] = (_Float16)(v - (float)hi);
  }
  const int base = ((ot * nks + ks) * 64 + t) * 8;
  *(half8*)&dh[base] = vh;
  *(half8*)&dl[base] = vl;
}

// ---------------------------------------------------------------- FPS ------
// One wave per batch, all-register, barrier-free (validated bit-exact).
__global__ __launch_bounds__(64) void fps_kernel(const float* __restrict__ xyz,
                                                 float* __restrict__ new_xyz) {
  const int b = blockIdx.x, lane = threadIdx.x;
  const float* xb = xyz + b * K_ * 3;
  __shared__ __align__(16) float4 pts[K_];  // 32 KB
  float px[32], py[32], pz[32], dist[32];
#pragma unroll
  for (int j = 0; j < 32; j++) {
    const int k = lane + 64 * j;
    const float x = xb[3 * k + 0];
    const float yv = xb[3 * k + 1];
    const float z = xb[3 * k + 2];
    px[j] = x; py[j] = yv; pz[j] = z;
    dist[j] = 1e10f;
    pts[k] = make_float4(x, yv, z, 0.f);
  }
  __syncthreads();
  int far = 0;
  for (int i = 0; i < P_; i++) {
    const float4 c = pts[far];  // uniform address -> LDS broadcast
    if (lane == 0) {
      float* nx = new_xyz + (b * P_ + i) * 3;
      nx[0] = c.x; nx[1] = c.y; nx[2] = c.z;
    }
    float bv = -1.f;
    int bj = 0;
#pragma unroll
    for (int j = 0; j < 32; j++) {
      const float d = sqdist_rn(px[j], py[j], pz[j], c.x, c.y, c.z);
      dist[j] = fminf(dist[j], d);
      if (dist[j] > bv) { bv = dist[j]; bj = j; }  // strict > keeps lowest j
    }
    const unsigned kg = (unsigned)(bj * 64 + lane);
    unsigned long long key =
        ((unsigned long long)__float_as_uint(bv) << 32) |
        (unsigned long long)(0xFFFFFFFFu - kg);
#pragma unroll
    for (int off = 1; off < 64; off <<= 1) {
      const unsigned long long o = __shfl_xor(key, off);
      key = (o > key) ? o : key;
    }
    far = (int)(0xFFFFFFFFu - (unsigned)(key & 0xFFFFFFFFull));
  }
}

// ---------------------------------------------------------- ball query -----
__global__ __launch_bounds__(256) void ballq_kernel(const float* __restrict__ xyz,
                                                    const float* __restrict__ new_xyz,
                                                    int* __restrict__ idxw) {
  const int b = blockIdx.x, t = threadIdx.x;
  __shared__ __align__(16) float pts[K_ * 4];
  const float* xb = xyz + b * K_ * 3;
#pragma unroll
  for (int j = 0; j < 8; j++) {
    int k = t + 256 * j;
    pts[4 * k + 0] = xb[3 * k + 0];
    pts[4 * k + 1] = xb[3 * k + 1];
    pts[4 * k + 2] = xb[3 * k + 2];
    pts[4 * k + 3] = 0.f;
  }
  __syncthreads();
  const float r2 = (float)(0.3 * 0.3);
  const int p = t;
  const float nx = new_xyz[(b * P_ + p) * 3 + 0];
  const float ny = new_xyz[(b * P_ + p) * 3 + 1];
  const float nz = new_xyz[(b * P_ + p) * 3 + 2];
  int* ob = idxw + (b * P_ + p) * S_;
  int cnt = 0, first = 0;
  for (int k = 0; k < K_; k++) {
    if (cnt >= S_) break;
    const float4 q = *(const float4*)&pts[4 * k];
    float d2 = sqdist_rn(q.x, q.y, q.z, nx, ny, nz);
    if (d2 < r2) {
      if (cnt == 0) first = k;
      ob[cnt] = k;
      cnt++;
    }
  }
  for (int s = cnt; s < S_; s++) ob[s] = first;
}

// ------------------------------------------------------------- SA MLP ------
// Split-f16 MFMA: D = Wh*Xh + Wh*Xl + Wl*Xh (error ~2^-22). 2 proposals
// (32 samples)/block. ROUND-8 CHANGE: 8 waves (512 thr) instead of 4; wave w
// owns o-tiles {2w, 2w+1} x both s-tiles. LDS/block unchanged (74 KB -> still
// 2 blocks/CU) and each weight tile still read once per block, but occupancy
// doubles: 8 -> 16 waves/CU (4/SIMD) to hide LDS->MFMA + prefetch latency
// (kernel was latency-bound: MfmaUtil 25%, VALU 18%, HBM 4%, occ 21.6%).
__global__ __launch_bounds__(512, 4) void sa_kernel(
    const float* __restrict__ xyz, const float* __restrict__ features,
    const _Float16* __restrict__ w1h, const _Float16* __restrict__ w1l,
    const _Float16* __restrict__ w2h, const _Float16* __restrict__ w2l,
    const _Float16* __restrict__ w3h, const _Float16* __restrict__ w3l,
    const float* __restrict__ bns, const float* __restrict__ mu,
    const float* __restrict__ bta, const float* __restrict__ new_xyz,
    const int* __restrict__ idxw, float* __restrict__ y) {
  const int blk = blockIdx.x;  // 4096
  const int b = blk >> 7, p0 = (blk & 127) * 2, t = threadIdx.x;
  __shared__ __align__(16) _Float16 X1h[32 * 296];
  __shared__ __align__(16) _Float16 X1l[32 * 296];
  __shared__ __align__(16) _Float16 X2h[32 * 264];
  __shared__ __align__(16) _Float16 X2l[32 * 264];
  __shared__ __align__(16) float red[2 * 256];
  __shared__ int k_sh[32];

  if (t < 32) k_sh[t] = idxw[(b * P_ + p0) * S_ + t];
  for (int u = t; u < 32 * 32; u += 512) {
    const int s = u >> 5, cc = 256 + (u & 31);
    if (cc >= 259) {
      X1h[s * 296 + cc] = (_Float16)0.f;
      X1l[s * 296 + cc] = (_Float16)0.f;
    }
  }
  __syncthreads();
  if (t < 32) {
    const int pl = t >> 4, k = k_sh[t];
    const float* xb = xyz + b * K_ * 3;
    const float* nx = new_xyz + (b * P_ + p0 + pl) * 3;
#pragma unroll
    for (int c = 0; c < 3; c++) {
      const float v = (xb[3 * k + c] - nx[c]) / 0.3f;
      const _Float16 hi = (_Float16)v;
      X1h[t * 296 + c] = hi;
      X1l[t * 296 + c] = (_Float16)(v - (float)hi);
    }
  }
  {
    // 512 threads: thread handles channel (t&255), half the samples (t>>8).
    const int cl = t & 255, hf = t >> 8;
    const float* fb = features + (size_t)b * C_ * K_ + (size_t)cl * K_;
    const int c = 3 + cl;
    const int s0 = hf * 16;
#pragma unroll 8
    for (int s = s0; s < s0 + 16; s++) {
      const float v = fb[k_sh[s]];
      const _Float16 hi = (_Float16)v;
      X1h[s * 296 + c] = hi;
      X1l[s * 296 + c] = (_Float16)(v - (float)hi);
    }
  }

  const int lane = t & 63, w = t >> 6;  // w in 0..7
  const int m = lane & 15, q = lane >> 4;

  f32x4 acc[2][2];
  half8 pAh[2], pAl[2];
#pragma unroll
  for (int i = 0; i < 2; i++) {
    const int off = (((2 * w + i) * 9) * 64 + lane) * 8;
    pAh[i] = *(const half8*)&w1h[off];
    pAl[i] = *(const half8*)&w1l[off];
  }
  __syncthreads();

#pragma unroll
  for (int l = 0; l < 3; l++) {
    const _Float16* Xih = (l == 1) ? X2h : X1h;
    const _Float16* Xil = (l == 1) ? X2l : X1l;
    const int XS = (l == 1) ? 264 : 296;
    const int nks = (l == 0) ? 9 : 8;
#pragma unroll
    for (int i = 0; i < 2; i++) {
      acc[i][0] = (f32x4){0.f, 0.f, 0.f, 0.f};
      acc[i][1] = (f32x4){0.f, 0.f, 0.f, 0.f};
    }
    for (int ks = 0; ks < nks; ks++) {
      half8 Ah[2], Al[2];
#pragma unroll
      for (int i = 0; i < 2; i++) { Ah[i] = pAh[i]; Al[i] = pAl[i]; }
      {
        int ln = l, kn = ks + 1;
        if (kn == nks) { ln = l + 1; kn = 0; }
        if (ln < 3) {
          const _Float16* Ph = (ln == 0) ? w1h : (ln == 1) ? w2h : w3h;
          const _Float16* Pl = (ln == 0) ? w1l : (ln == 1) ? w2l : w3l;
          const int nk2 = (ln == 0) ? 9 : 8;
#pragma unroll
          for (int i = 0; i < 2; i++) {
            const int off = (((2 * w + i) * nk2 + kn) * 64 + lane) * 8;
            pAh[i] = *(const half8*)&Ph[off];
            pAl[i] = *(const half8*)&Pl[off];
          }
        }
      }
      const int xo = ks * 32 + q * 8;
      const half8 Bh0 = *(const half8*)&Xih[m * XS + xo];
      const half8 Bl0 = *(const half8*)&Xil[m * XS + xo];
      const half8 Bh1 = *(const half8*)&Xih[(16 + m) * XS + xo];
      const half8 Bl1 = *(const half8*)&Xil[(16 + m) * XS + xo];
#pragma unroll
      for (int i = 0; i < 2; i++) {
        acc[i][0] = MFMA16(Ah[i], Bh0, acc[i][0], 0, 0, 0);
        acc[i][0] = MFMA16(Ah[i], Bl0, acc[i][0], 0, 0, 0);
        acc[i][0] = MFMA16(Al[i], Bh0, acc[i][0], 0, 0, 0);
        acc[i][1] = MFMA16(Ah[i], Bh1, acc[i][1], 0, 0, 0);
        acc[i][1] = MFMA16(Ah[i], Bl1, acc[i][1], 0, 0, 0);
        acc[i][1] = MFMA16(Al[i], Bh1, acc[i][1], 0, 0, 0);
      }
    }

    if (l < 2) {
      _Float16* Xoh = (l == 0) ? X2h : X1h;
      _Float16* Xol = (l == 0) ? X2l : X1l;
      const int XSo = (l == 0) ? 264 : 296;
#pragma unroll
      for (int i = 0; i < 2; i++) {
        const int ob = (2 * w + i) * 16 + q * 4;
        const f32x4 sc4 = *(const f32x4*)&bns[l * 256 + ob];
        const f32x4 m4 = *(const f32x4*)&mu[l * 256 + ob];
        const f32x4 b4 = *(const f32x4*)&bta[l * 256 + ob];
#pragma unroll
        for (int s = 0; s < 2; s++) {
          half4h vh, vl;
#pragma unroll
          for (int r = 0; r < 4; r++) {
            const float v = fmaxf((acc[i][s][r] - m4[r]) * sc4[r] + b4[r], 0.f);
            const _Float16 hi = (_Float16)v;
            vh[r] = hi;
            vl[r] = (_Float16)(v - (float)hi);
          }
          const int scol = s * 16 + m;
          *(half4h*)&Xoh[scol * XSo + ob] = vh;
          *(half4h*)&Xol[scol * XSo + ob] = vl;
        }
      }
      __syncthreads();
    } else {
#pragma unroll
      for (int i = 0; i < 2; i++)
#pragma unroll
        for (int s = 0; s < 2; s++)
#pragma unroll
          for (int r = 0; r < 4; r++) {
            float v = acc[i][s][r];
            v = fmaxf(v, __shfl_xor(v, 1));
            v = fmaxf(v, __shfl_xor(v, 2));
            v = fmaxf(v, __shfl_xor(v, 4));
            v = fmaxf(v, __shfl_xor(v, 8));
            acc[i][s][r] = v;
          }
      if (m == 0) {
#pragma unroll
        for (int i = 0; i < 2; i++) {
          const int ob = (2 * w + i) * 16 + q * 4;
          *(f32x4*)&red[ob] = acc[i][0];
          *(f32x4*)&red[256 + ob] = acc[i][1];
        }
      }
      __syncthreads();
      // 512 threads cover the 2x256 outputs in one shot
      const int pl = t >> 8, col = t & 255;
      const float sc2 = bns[512 + col];
      const float mu2 = mu[512 + col], bt2 = bta[512 + col];
      const float raw = red[pl * 256 + col];
      y[(b * P_ + p0 + pl) * 256 + col] = fmaxf((raw - mu2) * sc2 + bt2, 0.f);
    }
  }
}

// ------------------------------------------------- P-layers + all heads ----
// l0/l1: split-f16 MFMA (sa-proven; noise enters obj only through 2 BN+ReLU
// layers). l2 (obj-producing 119x256): EXACT round-7 f32 path, reading f32
// Y2 — no direct perturbation on argmin(obj). Round-6 bug (net_s stride 124
// vs ob<=127 collision) eliminated: l2 writes only o<119, stride 120.
__global__ __launch_bounds__(256, 2) void phead_kernel(
    const float* __restrict__ y, const _Float16* __restrict__ p1h,
    const _Float16* __restrict__ p1l, const _Float16* __restrict__ p2h,
    const _Float16* __restrict__ p2l, const float* __restrict__ pw3,
    const float* __restrict__ pb3, const float* __restrict__ bns,
    const float* __restrict__ pm, const float* __restrict__ pb,
    const float* __restrict__ new_xyz, const float* __restrict__ msa,
    float* __restrict__ out) {
  const int blk = blockIdx.x;  // 512
  const int b = blk >> 4, p0 = (blk & 15) * 16, t = threadIdx.x;
  // hand-packed LDS: Wt (l2 only) aliases X0/H (dead by l2)
  __shared__ __align__(16) char smem[58624];
  _Float16* X0h = (_Float16*)smem;             // 16*264*2 = 8448
  _Float16* X0l = (_Float16*)(smem + 8448);    // 8448
  _Float16* Hh  = (_Float16*)(smem + 16896);   // 8448
  _Float16* Hl  = (_Float16*)(smem + 25344);   // 8448 (ends 33792)
  float*    Wt  = (float*)smem;                // 256*20*4 = 20480 (alias)
  float*    Y2  = (float*)(smem + 33792);      // 16*260*4 = 16640
  float*    net_s = (float*)(smem + 50432);    // 16*120*4 = 7680

  {
#pragma unroll 4
    for (int s = 0; s < 16; s++) {
      const float v = y[(size_t)(b * P_ + p0 + s) * C_ + t];
      const _Float16 hi = (_Float16)v;
      X0h[s * 264 + t] = hi;
      X0l[s * 264 + t] = (_Float16)(v - (float)hi);
    }
  }
  const int lane = t & 63, w = t >> 6;
  const int m = lane & 15, q = lane >> 4;

  f32x4 acc[4];
  half8 pAh[4], pAl[4];
#pragma unroll
  for (int i = 0; i < 4; i++) {
    const int off = (((4 * w + i) * 8) * 64 + lane) * 8;
    pAh[i] = *(const half8*)&p1h[off];
    pAl[i] = *(const half8*)&p1l[off];
  }
  __syncthreads();

#pragma unroll
  for (int l = 0; l < 2; l++) {
    const _Float16* Xih = l ? Hh : X0h;
    const _Float16* Xil = l ? Hl : X0l;
#pragma unroll
    for (int i = 0; i < 4; i++) acc[i] = (f32x4){0.f, 0.f, 0.f, 0.f};
    for (int ks = 0; ks < 8; ks++) {
      half8 Ah[4], Al[4];
#pragma unroll
      for (int i = 0; i < 4; i++) { Ah[i] = pAh[i]; Al[i] = pAl[i]; }
      {
        int ln = l, kn = ks + 1;
        if (kn == 8) { ln = l + 1; kn = 0; }
        if (ln < 2) {
          const _Float16* Ph = ln ? p2h : p1h;
          const _Float16* Pl = ln ? p2l : p1l;
#pragma unroll
          for (int i = 0; i < 4; i++) {
            const int off = (((4 * w + i) * 8 + kn) * 64 + lane) * 8;
            pAh[i] = *(const half8*)&Ph[off];
            pAl[i] = *(const half8*)&Pl[off];
          }
        }
      }
      const int xo = ks * 32 + q * 8;
      const half8 Bh = *(const half8*)&Xih[m * 264 + xo];
      const half8 Bl = *(const half8*)&Xil[m * 264 + xo];
#pragma unroll
      for (int i = 0; i < 4; i++) {
        acc[i] = MFMA16(Ah[i], Bh, acc[i], 0, 0, 0);
        acc[i] = MFMA16(Ah[i], Bl, acc[i], 0, 0, 0);
        acc[i] = MFMA16(Al[i], Bh, acc[i], 0, 0, 0);
      }
    }
    // epilogue: BN + ReLU; l0 -> H (f16 split), l1 -> Y2 (f32)
#pragma unroll
    for (int i = 0; i < 4; i++) {
      const int ob = (4 * w + i) * 16 + q * 4;
      const f32x4 sc4 = *(const f32x4*)&bns[768 + l * 256 + ob];
      const f32x4 m4 = *(const f32x4*)&pm[l * 256 + ob];
      const f32x4 b4 = *(const f32x4*)&pb[l * 256 + ob];
      if (l == 0) {
        half4h vh, vl;
#pragma unroll
        for (int r = 0; r < 4; r++) {
          const float v = fmaxf((acc[i][r] - m4[r]) * sc4[r] + b4[r], 0.f);
          const _Float16 hi = (_Float16)v;
          vh[r] = hi;
          vl[r] = (_Float16)(v - (float)hi);
        }
        *(half4h*)&Hh[m * 264 + ob] = vh;
        *(half4h*)&Hl[m * 264 + ob] = vl;
      } else {
        f32x4 r4;
#pragma unroll
        for (int r = 0; r < 4; r++)
          r4[r] = fmaxf((acc[i][r] - m4[r]) * sc4[r] + b4[r], 0.f);
        *(f32x4*)&Y2[m * 260 + ob] = r4;
      }
    }
    __syncthreads();
  }

  // final layer (f32, round-7-exact): 119 outputs from Y2; Wt aliases X0/H
  {
    const int o = t & 127, ph = t >> 7;
    float a3[8];
#pragma unroll
    for (int pp = 0; pp < 8; pp++) a3[pp] = 0.f;
    for (int tile = 0; tile < 16; tile++) {
      const int c0 = tile * 16;
      for (int u = t; u < 119 * 4; u += 256) {
        int oo = u >> 2, qq = u & 3;
        *(float4*)&Wt[oo * 20 + qq * 4] =
            *(const float4*)(pw3 + oo * 256 + c0 + qq * 4);
      }
      __syncthreads();
      if (o < 119) {
#pragma unroll
        for (int j4 = 0; j4 < 4; j4++) {
          const float4 wv = *(const float4*)&Wt[o * 20 + j4 * 4];
#pragma unroll
          for (int pp = 0; pp < 8; pp++) {
            const float4 xv =
                *(const float4*)&Y2[(ph * 8 + pp) * 260 + c0 + j4 * 4];
            a3[pp] = fmaf(wv.x, xv.x, a3[pp]);
            a3[pp] = fmaf(wv.y, xv.y, a3[pp]);
            a3[pp] = fmaf(wv.z, xv.z, a3[pp]);
            a3[pp] = fmaf(wv.w, xv.w, a3[pp]);
          }
        }
      }
      __syncthreads();
    }
    if (o < 119) {
      const float bb = pb3[o];
#pragma unroll
      for (int pp = 0; pp < 8; pp++)
        net_s[(ph * 8 + pp) * 120 + o] = a3[pp] + bb;
    }
  }
  __syncthreads();

  if (t < 16) {
    const int gi = b * P_ + p0 + t;
    const float* nr = &net_s[t * 120];
    const float nx = new_xyz[gi * 3 + 0];
    const float ny = new_xyz[gi * 3 + 1];
    const float nz = new_xyz[gi * 3 + 2];
    const float obj0 = nr[0], obj1 = nr[1];
    out[OFF0 + gi * 2 + 0] = obj0;
    out[OFF0 + gi * 2 + 1] = obj1;
    const float cx = nx + nr[2], cy = ny + nr[3], cz = nz + nr[4];
    out[OFF1 + gi * 3 + 0] = cx;
    out[OFF1 + gi * 3 + 1] = cy;
    out[OFF1 + gi * 3 + 2] = cz;
    float bv = -1e30f;
    int bi = 0;
#pragma unroll
    for (int i = 0; i < 18; i++) {
      float v = nr[29 + i];
      out[OFF2 + gi * 18 + i] = v;
      if (v > bv) { bv = v; bi = i; }
    }
#pragma unroll
    for (int i = 0; i < 18; i++)
#pragma unroll
      for (int j = 0; j < 3; j++)
        out[OFF3 + gi * 54 + i * 3 + j] =
            __fmul_rn(nr[47 + i * 3 + j], msa[i * 3 + j]);
    float ps[3];
#pragma unroll
    for (int j = 0; j < 3; j++) {
      ps[j] = __fadd_rn(__fmul_rn(nr[47 + bi * 3 + j], msa[bi * 3 + j]),
                        msa[bi * 3 + j]);
      out[OFF4 + gi * 3 + j] = ps[j];
    }
    float sm = -1e30f;
#pragma unroll
    for (int i = 0; i < 18; i++) {
      float v = nr[101 + i];
      out[OFF5 + gi * 18 + i] = v;
      out[OFF7 + gi * 19 + i] = v;
      sm = fmaxf(sm, v);
    }
    out[OFF7 + gi * 19 + 18] = (obj0 <= obj1) ? 0.f : 1e10f;
    const float cc0 = cx, cc1 = cz, cc2 = -cy;
    const float sxk[8] = {1, 1, -1, -1, 1, 1, -1, -1};
    const float syk[8] = {1, 1, 1, 1, -1, -1, -1, -1};
    const float szk[8] = {1, -1, -1, 1, 1, -1, -1, 1};
#pragma unroll
    for (int k = 0; k < 8; k++) {
      out[OFF6 + gi * 24 + 3 * k + 0] = cc0 + ps[0] * sxk[k] * 0.5f;
      out[OFF6 + gi * 24 + 3 * k + 1] = cc1 + ps[2] * syk[k] * 0.5f;
      out[OFF6 + gi * 24 + 3 * k + 2] = cc2 + ps[1] * szk[k] * 0.5f;
    }
    {
      const float m2 = fmaxf(obj0, obj1);
      const float e0 = expf(obj0 - m2), e1 = expf(obj1 - m2);
      out[OFF8 + gi] = e1 / (e0 + e1);
    }
    {
      float ev[18], es = 0.f;
#pragma unroll
      for (int i = 0; i < 18; i++) {
        ev[i] = expf(nr[101 + i] - sm);
        es += ev[i];
      }
#pragma unroll
      for (int i = 0; i < 18; i++) out[OFF9 + gi * 18 + i] = ev[i] / es;
    }
  }
}

// ---------------------------------------------------------------------------
extern "C" void kernel_launch(void* const* d_in, const int* in_sizes, int n_in,
                              void* d_out, int out_size, void* d_ws,
                              size_t ws_size, hipStream_t stream) {
  (void)in_sizes; (void)n_in; (void)out_size; (void)ws_size;
  const float* xyz      = (const float*)d_in[0];
  const float* features = (const float*)d_in[1];
  const float* w1       = (const float*)d_in[2];
  const float* w2       = (const float*)d_in[3];
  const float* w3       = (const float*)d_in[4];
  const float* gma      = (const float*)d_in[5];
  const float* bta      = (const float*)d_in[6];
  const float* mu       = (const float*)d_in[7];
  const float* var      = (const float*)d_in[8];
  const float* pw1      = (const float*)d_in[9];
  const float* pw2      = (const float*)d_in[10];
  const float* pw3      = (const float*)d_in[11];
  const float* pb3      = (const float*)d_in[12];
  const float* pg       = (const float*)d_in[13];
  const float* pb       = (const float*)d_in[14];
  const float* pm       = (const float*)d_in[15];
  const float* pv       = (const float*)d_in[16];
  const float* msa      = (const float*)d_in[17];
  float* out = (float*)d_out;

  char* ws = (char*)d_ws;
  float*     new_xyz = (float*)ws;                   // 98304 B
  int*       idxw    = (int*)(ws + 98304);           // 524288 B
  float*     yb      = (float*)(ws + 622592);        // 8388608 B
  _Float16*  w1h     = (_Float16*)(ws + 9011200);    // 147456 B
  _Float16*  w1l     = (_Float16*)(ws + 9158656);    // 147456 B
  _Float16*  w2h     = (_Float16*)(ws + 9306112);    // 131072 B
  _Float16*  w2l     = (_Float16*)(ws + 9437184);    // 131072 B
  _Float16*  w3h     = (_Float16*)(ws + 9568256);    // 131072 B
  _Float16*  w3l     = (_Float16*)(ws + 9699328);    // 131072 B
  float*     bns     = (float*)(ws + 9830400);       // 5120 B (1280 f)
  _Float16*  p1h     = (_Float16*)(ws + 9835520);    // 131072 B
  _Float16*  p1l     = (_Float16*)(ws + 9966592);    // 131072 B
  _Float16*  p2h     = (_Float16*)(ws + 10097664);   // 131072 B
  _Float16*  p2l     = (_Float16*)(ws + 10228736);   // 131072 B -> 10359808

  wsplit_kernel<<<657, 64, 0, stream>>>(w1, w2, w3, pw1, pw2, gma, var, pg,
                                        pv, w1h, w1l, w2h, w2l, w3h, w3l, p1h,
                                        p1l, p2h, p2l, bns);
  fps_kernel<<<B_, 64, 0, stream>>>(xyz, new_xyz);
  ballq_kernel<<<B_, 256, 0, stream>>>(xyz, new_xyz, idxw);
  sa_kernel<<<B_ * 128, 512, 0, stream>>>(xyz, features, w1h, w1l, w2h, w2l,
                                          w3h, w3l, bns, mu, bta, new_xyz,
                                          idxw, yb);
  phead_kernel<<<B_ * 16, 256, 0, stream>>>(yb, p1h, p1l, p2h, p2l, pw3, pb3,
                                            bns, pm, pb, new_xyz, msa, out);
}

// Round 2
// 629.642 us; speedup vs baseline: 1.2310x; 1.2087x over previous
//
#include <hip/hip_runtime.h>
#include <math.h>

#define B_   32
#define K_   2048
#define C_   256
#define P_   256
#define S_   16
#define OUTC 119

// output offsets (floats)
#define OFF0 0        // obj        (B,P,2)
#define OFF1 16384    // center     (B,P,3)
#define OFF2 40960    // size_scores(B,P,18)
#define OFF3 188416   // size_res   (B,P,18,3)
#define OFF4 630784   // pred_size  (B,P,3)
#define OFF5 655360   // sem        (B,P,18)
#define OFF6 802816   // corners    (B,P,8,3)
#define OFF7 999424   // sem_logits (B,P,19)
#define OFF8 1155072  // obj_prob   (B,P)
#define OFF9 1163264  // sem_prob   (B,P,18)

typedef _Float16 half8  __attribute__((ext_vector_type(8)));
typedef _Float16 half4h __attribute__((ext_vector_type(4)));
typedef float    f32x4  __attribute__((ext_vector_type(4)));
#define MFMA16 __builtin_amdgcn_mfma_f32_16x16x32_f16

__device__ __forceinline__ float sqdist_rn(float ax, float ay, float az,
                                           float bx, float by, float bz) {
  float dx = __fsub_rn(ax, bx), dy = __fsub_rn(ay, by), dz = __fsub_rn(az, bz);
  return __fadd_rn(__fadd_rn(__fmul_rn(dx, dx), __fmul_rn(dy, dy)),
                   __fmul_rn(dz, dz));
}

__device__ __forceinline__ unsigned umax_(unsigned a, unsigned b) {
  return a > b ? a : b;
}
__device__ __forceinline__ unsigned umin_(unsigned a, unsigned b) {
  return a < b ? a : b;
}
// Wave64 u32 max via DPP (row_shr 1/2/4/8 + row_bcast15/31); result valid in
// lane 63. bound_ctrl=false -> invalid source lanes contribute `old`
// (identity). This is the LLVM AMDGPUAtomicOptimizer reduction pattern.
__device__ __forceinline__ unsigned wave_red_umax(unsigned x) {
  x = umax_(x, (unsigned)__builtin_amdgcn_update_dpp(0, (int)x, 0x111, 0xf, 0xf, false));
  x = umax_(x, (unsigned)__builtin_amdgcn_update_dpp(0, (int)x, 0x112, 0xf, 0xf, false));
  x = umax_(x, (unsigned)__builtin_amdgcn_update_dpp(0, (int)x, 0x114, 0xf, 0xf, false));
  x = umax_(x, (unsigned)__builtin_amdgcn_update_dpp(0, (int)x, 0x118, 0xf, 0xf, false));
  x = umax_(x, (unsigned)__builtin_amdgcn_update_dpp(0, (int)x, 0x142, 0xf, 0xf, false));
  x = umax_(x, (unsigned)__builtin_amdgcn_update_dpp(0, (int)x, 0x143, 0xf, 0xf, false));
  return x;
}
__device__ __forceinline__ unsigned wave_red_umin(unsigned x) {
  x = umin_(x, (unsigned)__builtin_amdgcn_update_dpp(-1, (int)x, 0x111, 0xf, 0xf, false));
  x = umin_(x, (unsigned)__builtin_amdgcn_update_dpp(-1, (int)x, 0x112, 0xf, 0xf, false));
  x = umin_(x, (unsigned)__builtin_amdgcn_update_dpp(-1, (int)x, 0x114, 0xf, 0xf, false));
  x = umin_(x, (unsigned)__builtin_amdgcn_update_dpp(-1, (int)x, 0x118, 0xf, 0xf, false));
  x = umin_(x, (unsigned)__builtin_amdgcn_update_dpp(-1, (int)x, 0x142, 0xf, 0xf, false));
  x = umin_(x, (unsigned)__builtin_amdgcn_update_dpp(-1, (int)x, 0x143, 0xf, 0xf, false));
  return x;
}

// ------------------------------------------- weight split to f16 hi/lo -----
// Fragment-order layout: Wf[tile = ot*nks + ks][lane][8] -> A-frag load is
// one coalesced 1KB wave read. sa l0 padded K 259->288 (9 k-steps).
// Sub-blocks: 0..143 w1, 144..271 w2, 272..399 w3, 400..527 pw1,
// 528..655 pw2, 656: BN scale prep. pw3 stays f32 (l2 exact).
__device__ __forceinline__ void wsplit_body(
    int r, int t, const float* __restrict__ w1, const float* __restrict__ w2,
    const float* __restrict__ w3, const float* __restrict__ pw1,
    const float* __restrict__ pw2, const float* __restrict__ gma,
    const float* __restrict__ var, const float* __restrict__ pg,
    const float* __restrict__ pv, _Float16* __restrict__ w1h,
    _Float16* __restrict__ w1l, _Float16* __restrict__ w2h,
    _Float16* __restrict__ w2l, _Float16* __restrict__ w3h,
    _Float16* __restrict__ w3l, _Float16* __restrict__ p1h,
    _Float16* __restrict__ p1l, _Float16* __restrict__ p2h,
    _Float16* __restrict__ p2l, float* __restrict__ bns) {
  if (r == 656) {
    for (int u = t; u < 768; u += 64) bns[u] = gma[u] / sqrtf(var[u] + 1e-5f);
    for (int u = t; u < 512; u += 64)
      bns[768 + u] = pg[u] / sqrtf(pv[u] + 1e-5f);
    return;
  }
  const float* src;
  _Float16 *dh, *dl;
  int ot, ks, nks, K;
  if (r < 144) {
    src = w1; dh = w1h; dl = w1l; ot = r / 9; ks = r % 9; nks = 9; K = 259;
  } else if (r < 272) {
    const int rr = r - 144;
    src = w2; dh = w2h; dl = w2l; ot = rr >> 3; ks = rr & 7; nks = 8; K = 256;
  } else if (r < 400) {
    const int rr = r - 272;
    src = w3; dh = w3h; dl = w3l; ot = rr >> 3; ks = rr & 7; nks = 8; K = 256;
  } else if (r < 528) {
    const int rr = r - 400;
    src = pw1; dh = p1h; dl = p1l; ot = rr >> 3; ks = rr & 7; nks = 8; K = 256;
  } else {
    const int rr = r - 528;
    src = pw2; dh = p2h; dl = p2l; ot = rr >> 3; ks = rr & 7; nks = 8; K = 256;
  }
  const int m = t & 15, q = t >> 4;
  const float* row = src + (ot * 16 + m) * K;
  half8 vh, vl;
#pragma unroll
  for (int j = 0; j < 8; j++) {
    const int c = ks * 32 + q * 8 + j;
    const float v = (c < K) ? row[c] : 0.f;
    const _Float16 hi = (_Float16)v;
    vh[j] = hi;
    vl[j] = (_Float16)(v - (float)hi);
  }
  const int base = ((ot * nks + ks) * 64 + t) * 8;
  *(half8*)&dh[base] = vh;
  *(half8*)&dl[base] = vl;
}

// ------------------------------------------- fused FPS (4-wave) + wsplit ---
// Blocks 0..31: FPS, one block (4 waves, 256 thr) per batch. Each thread owns
// 8 points (k = t + 256*j; lowest-j == lowest-k, preserving argmax tie-break).
// Reduce: exact two-phase u32 (dist>=0 -> bits order-isomorphic): DPP max of
// dist-bits, then DPP min of k among lanes equal to max; cross-wave combine
// via parity-double-buffered 4-entry LDS slot (1 barrier/iter).
// Blocks 32..196: wsplit, 4 64-thread sub-blocks each (independent work,
// overlapped under FPS to save a launch).
__global__ __launch_bounds__(256) void fused_pre_kernel(
    const float* __restrict__ xyz, float* __restrict__ new_xyz,
    const float* __restrict__ w1, const float* __restrict__ w2,
    const float* __restrict__ w3, const float* __restrict__ pw1,
    const float* __restrict__ pw2, const float* __restrict__ gma,
    const float* __restrict__ var, const float* __restrict__ pg,
    const float* __restrict__ pv, _Float16* __restrict__ w1h,
    _Float16* __restrict__ w1l, _Float16* __restrict__ w2h,
    _Float16* __restrict__ w2l, _Float16* __restrict__ w3h,
    _Float16* __restrict__ w3l, _Float16* __restrict__ p1h,
    _Float16* __restrict__ p1l, _Float16* __restrict__ p2h,
    _Float16* __restrict__ p2l, float* __restrict__ bns) {
  __shared__ __align__(16) float4 pts[K_];  // 32 KB (FPS blocks only)
  __shared__ uint2 redw[2][4];

  if (blockIdx.x >= 32) {
    const int sub = (blockIdx.x - 32) * 4 + (threadIdx.x >> 6);
    if (sub < 657)
      wsplit_body(sub, threadIdx.x & 63, w1, w2, w3, pw1, pw2, gma, var, pg,
                  pv, w1h, w1l, w2h, w2l, w3h, w3l, p1h, p1l, p2h, p2l, bns);
    return;
  }

  const int b = blockIdx.x, t = threadIdx.x;
  const int lane = t & 63, w = t >> 6;
  const float* xb = xyz + b * K_ * 3;
  float px[8], py[8], pz[8], dist[8];
#pragma unroll
  for (int j = 0; j < 8; j++) {
    const int k = t + 256 * j;
    const float x = xb[3 * k + 0];
    const float yv = xb[3 * k + 1];
    const float z = xb[3 * k + 2];
    px[j] = x; py[j] = yv; pz[j] = z;
    dist[j] = 1e10f;
    pts[k] = make_float4(x, yv, z, 0.f);
  }
  __syncthreads();
  int far = 0;
  for (int i = 0; i < P_; i++) {
    const float4 c = pts[far];  // uniform address -> LDS broadcast
    if (t == 0) {
      float* nx = new_xyz + (b * P_ + i) * 3;
      nx[0] = c.x; nx[1] = c.y; nx[2] = c.z;
    }
    float bv = -1.f;
    int bj = 0;
#pragma unroll
    for (int j = 0; j < 8; j++) {
      const float d = sqdist_rn(px[j], py[j], pz[j], c.x, c.y, c.z);
      dist[j] = fminf(dist[j], d);
      if (dist[j] > bv) { bv = dist[j]; bj = j; }  // strict > keeps lowest j
    }
    const unsigned bvb = __float_as_uint(bv);
    const unsigned gw = wave_red_umax(bvb);
    const unsigned gmaxw = (unsigned)__builtin_amdgcn_readlane((int)gw, 63);
    const unsigned kg = (unsigned)(bj * 256 + t);  // == global point index k
    const unsigned key2 = (bvb == gmaxw) ? kg : 0xFFFFFFFFu;
    const unsigned kw = wave_red_umin(key2);
    if (lane == 63) redw[i & 1][w] = make_uint2(gmaxw, kw);
    __syncthreads();
    const uint2 r0 = redw[i & 1][0], r1 = redw[i & 1][1];
    const uint2 r2 = redw[i & 1][2], r3 = redw[i & 1][3];
    const unsigned g = umax_(umax_(r0.x, r1.x), umax_(r2.x, r3.x));
    unsigned fk = 0xFFFFFFFFu;
    if (r0.x == g) fk = umin_(fk, r0.y);
    if (r1.x == g) fk = umin_(fk, r1.y);
    if (r2.x == g) fk = umin_(fk, r2.y);
    if (r3.x == g) fk = umin_(fk, r3.y);
    far = (int)fk;
  }
}

// ---------------------------------------------------------- ball query -----
__global__ __launch_bounds__(256) void ballq_kernel(const float* __restrict__ xyz,
                                                    const float* __restrict__ new_xyz,
                                                    int* __restrict__ idxw) {
  const int b = blockIdx.x, t = threadIdx.x;
  __shared__ __align__(16) float pts[K_ * 4];
  const float* xb = xyz + b * K_ * 3;
#pragma unroll
  for (int j = 0; j < 8; j++) {
    int k = t + 256 * j;
    pts[4 * k + 0] = xb[3 * k + 0];
    pts[4 * k + 1] = xb[3 * k + 1];
    pts[4 * k + 2] = xb[3 * k + 2];
    pts[4 * k + 3] = 0.f;
  }
  __syncthreads();
  const float r2 = (float)(0.3 * 0.3);
  const int p = t;
  const float nx = new_xyz[(b * P_ + p) * 3 + 0];
  const float ny = new_xyz[(b * P_ + p) * 3 + 1];
  const float nz = new_xyz[(b * P_ + p) * 3 + 2];
  int* ob = idxw + (b * P_ + p) * S_;
  int cnt = 0, first = 0;
  for (int k = 0; k < K_; k++) {
    if (cnt >= S_) break;
    const float4 q = *(const float4*)&pts[4 * k];
    float d2 = sqdist_rn(q.x, q.y, q.z, nx, ny, nz);
    if (d2 < r2) {
      if (cnt == 0) first = k;
      ob[cnt] = k;
      cnt++;
    }
  }
  for (int s = cnt; s < S_; s++) ob[s] = first;
}

// ------------------------------------------------------------- SA MLP ------
// Split-f16 MFMA: D = Wh*Xh + Wh*Xl + Wl*Xh (error ~2^-22). 2 proposals
// (32 samples)/block, 8 waves (512 thr); wave w owns o-tiles {2w,2w+1}.
// ROUND-2 CHANGE: depth-2 weight-prefetch ring rA[2][i] (parity = flat-step
// & 1, fully unrolled -> all ring indices compile-time, no scratch). Theory:
// kernel stalls on L2 weight-load latency (~200cy) with only ~60cy of
// depth-1 cover; MfmaUtil 27% ~= 58/200. Doubling the pipeline depth covers
// the L2 latency. VGPR 64 -> ~100, still <=128 (4 waves/SIMD; LDS caps
// occupancy at 2 blocks/CU regardless).
__global__ __launch_bounds__(512, 4) void sa_kernel(
    const float* __restrict__ xyz, const float* __restrict__ features,
    const _Float16* __restrict__ w1h, const _Float16* __restrict__ w1l,
    const _Float16* __restrict__ w2h, const _Float16* __restrict__ w2l,
    const _Float16* __restrict__ w3h, const _Float16* __restrict__ w3l,
    const float* __restrict__ bns, const float* __restrict__ mu,
    const float* __restrict__ bta, const float* __restrict__ new_xyz,
    const int* __restrict__ idxw, float* __restrict__ y) {
  const int blk = blockIdx.x;  // 4096
  const int b = blk >> 7, p0 = (blk & 127) * 2, t = threadIdx.x;
  __shared__ __align__(16) _Float16 X1h[32 * 296];
  __shared__ __align__(16) _Float16 X1l[32 * 296];
  __shared__ __align__(16) _Float16 X2h[32 * 264];
  __shared__ __align__(16) _Float16 X2l[32 * 264];
  __shared__ __align__(16) float red[2 * 256];
  __shared__ int k_sh[32];

  if (t < 32) k_sh[t] = idxw[(b * P_ + p0) * S_ + t];
  for (int u = t; u < 32 * 32; u += 512) {
    const int s = u >> 5, cc = 256 + (u & 31);
    if (cc >= 259) {
      X1h[s * 296 + cc] = (_Float16)0.f;
      X1l[s * 296 + cc] = (_Float16)0.f;
    }
  }
  __syncthreads();
  if (t < 32) {
    const int pl = t >> 4, k = k_sh[t];
    const float* xb = xyz + b * K_ * 3;
    const float* nx = new_xyz + (b * P_ + p0 + pl) * 3;
#pragma unroll
    for (int c = 0; c < 3; c++) {
      const float v = (xb[3 * k + c] - nx[c]) / 0.3f;
      const _Float16 hi = (_Float16)v;
      X1h[t * 296 + c] = hi;
      X1l[t * 296 + c] = (_Float16)(v - (float)hi);
    }
  }
  {
    // 512 threads: thread handles channel (t&255), half the samples (t>>8).
    const int cl = t & 255, hf = t >> 8;
    const float* fb = features + (size_t)b * C_ * K_ + (size_t)cl * K_;
    const int c = 3 + cl;
    const int s0 = hf * 16;
#pragma unroll 8
    for (int s = s0; s < s0 + 16; s++) {
      const float v = fb[k_sh[s]];
      const _Float16 hi = (_Float16)v;
      X1h[s * 296 + c] = hi;
      X1l[s * 296 + c] = (_Float16)(v - (float)hi);
    }
  }

  const int lane = t & 63, w = t >> 6;  // w in 0..7
  const int m = lane & 15, q = lane >> 4;

  f32x4 acc[2][2];
  half8 rAh[2][2], rAl[2][2];  // [parity][i] depth-2 prefetch ring
#pragma unroll
  for (int i = 0; i < 2; i++) {
    rAh[0][i] = *(const half8*)&w1h[(((2 * w + i) * 9 + 0) * 64 + lane) * 8];
    rAl[0][i] = *(const half8*)&w1l[(((2 * w + i) * 9 + 0) * 64 + lane) * 8];
    rAh[1][i] = *(const half8*)&w1h[(((2 * w + i) * 9 + 1) * 64 + lane) * 8];
    rAl[1][i] = *(const half8*)&w1l[(((2 * w + i) * 9 + 1) * 64 + lane) * 8];
  }
  __syncthreads();

#pragma unroll
  for (int l = 0; l < 3; l++) {
    const _Float16* Xih = (l == 1) ? X2h : X1h;
    const _Float16* Xil = (l == 1) ? X2l : X1l;
    const int XS = (l == 1) ? 264 : 296;
    const int nks = (l == 0) ? 9 : 8;
    const int base = (l == 0) ? 0 : (l == 1) ? 9 : 17;  // flat step base
#pragma unroll
    for (int i = 0; i < 2; i++) {
      acc[i][0] = (f32x4){0.f, 0.f, 0.f, 0.f};
      acc[i][1] = (f32x4){0.f, 0.f, 0.f, 0.f};
    }
#pragma unroll
    for (int ks = 0; ks < nks; ks++) {
      const int par = (base + ks) & 1;  // compile-time under full unroll
      half8 Ah[2], Al[2];
#pragma unroll
      for (int i = 0; i < 2; i++) { Ah[i] = rAh[par][i]; Al[i] = rAl[par][i]; }
      {
        // prefetch flat-step + 2 into the parity slot just vacated
        int ln = l, kn = ks + 2;
        if (kn >= nks) { kn -= nks; ln = l + 1; }
        if (ln < 3) {
          const _Float16* Ph = (ln == 0) ? w1h : (ln == 1) ? w2h : w3h;
          const _Float16* Pl = (ln == 0) ? w1l : (ln == 1) ? w2l : w3l;
          const int nk2 = (ln == 0) ? 9 : 8;
#pragma unroll
          for (int i = 0; i < 2; i++) {
            const int off = (((2 * w + i) * nk2 + kn) * 64 + lane) * 8;
            rAh[par][i] = *(const half8*)&Ph[off];
            rAl[par][i] = *(const half8*)&Pl[off];
          }
        }
      }
      const int xo = ks * 32 + q * 8;
      const half8 Bh0 = *(const half8*)&Xih[m * XS + xo];
      const half8 Bl0 = *(const half8*)&Xil[m * XS + xo];
      const half8 Bh1 = *(const half8*)&Xih[(16 + m) * XS + xo];
      const half8 Bl1 = *(const half8*)&Xil[(16 + m) * XS + xo];
#pragma unroll
      for (int i = 0; i < 2; i++) {
        acc[i][0] = MFMA16(Ah[i], Bh0, acc[i][0], 0, 0, 0);
        acc[i][0] = MFMA16(Ah[i], Bl0, acc[i][0], 0, 0, 0);
        acc[i][0] = MFMA16(Al[i], Bh0, acc[i][0], 0, 0, 0);
        acc[i][1] = MFMA16(Ah[i], Bh1, acc[i][1], 0, 0, 0);
        acc[i][1] = MFMA16(Ah[i], Bl1, acc[i][1], 0, 0, 0);
        acc[i][1] = MFMA16(Al[i], Bh1, acc[i][1], 0, 0, 0);
      }
    }

    if (l < 2) {
      _Float16* Xoh = (l == 0) ? X2h : X1h;
      _Float16* Xol = (l == 0) ? X2l : X1l;
      const int XSo = (l == 0) ? 264 : 296;
#pragma unroll
      for (int i = 0; i < 2; i++) {
        const int ob = (2 * w + i) * 16 + q * 4;
        const f32x4 sc4 = *(const f32x4*)&bns[l * 256 + ob];
        const f32x4 m4 = *(const f32x4*)&mu[l * 256 + ob];
        const f32x4 b4 = *(const f32x4*)&bta[l * 256 + ob];
#pragma unroll
        for (int s = 0; s < 2; s++) {
          half4h vh, vl;
#pragma unroll
          for (int r = 0; r < 4; r++) {
            const float v = fmaxf((acc[i][s][r] - m4[r]) * sc4[r] + b4[r], 0.f);
            const _Float16 hi = (_Float16)v;
            vh[r] = hi;
            vl[r] = (_Float16)(v - (float)hi);
          }
          const int scol = s * 16 + m;
          *(half4h*)&Xoh[scol * XSo + ob] = vh;
          *(half4h*)&Xol[scol * XSo + ob] = vl;
        }
      }
      __syncthreads();
    } else {
#pragma unroll
      for (int i = 0; i < 2; i++)
#pragma unroll
        for (int s = 0; s < 2; s++)
#pragma unroll
          for (int r = 0; r < 4; r++) {
            float v = acc[i][s][r];
            v = fmaxf(v, __shfl_xor(v, 1));
            v = fmaxf(v, __shfl_xor(v, 2));
            v = fmaxf(v, __shfl_xor(v, 4));
            v = fmaxf(v, __shfl_xor(v, 8));
            acc[i][s][r] = v;
          }
      if (m == 0) {
#pragma unroll
        for (int i = 0; i < 2; i++) {
          const int ob = (2 * w + i) * 16 + q * 4;
          *(f32x4*)&red[ob] = acc[i][0];
          *(f32x4*)&red[256 + ob] = acc[i][1];
        }
      }
      __syncthreads();
      // 512 threads cover the 2x256 outputs in one shot
      const int pl = t >> 8, col = t & 255;
      const float sc2 = bns[512 + col];
      const float mu2 = mu[512 + col], bt2 = bta[512 + col];
      const float raw = red[pl * 256 + col];
      y[(b * P_ + p0 + pl) * 256 + col] = fmaxf((raw - mu2) * sc2 + bt2, 0.f);
    }
  }
}

// ------------------------------------------------- P-layers + all heads ----
// l0/l1: split-f16 MFMA (sa-proven; noise enters obj only through 2 BN+ReLU
// layers). l2 (obj-producing 119x256): EXACT round-7 f32 path, reading f32
// Y2 — no direct perturbation on argmin(obj). Round-6 bug (net_s stride 124
// vs ob<=127 collision) eliminated: l2 writes only o<119, stride 120.
__global__ __launch_bounds__(256, 2) void phead_kernel(
    const float* __restrict__ y, const _Float16* __restrict__ p1h,
    const _Float16* __restrict__ p1l, const _Float16* __restrict__ p2h,
    const _Float16* __restrict__ p2l, const float* __restrict__ pw3,
    const float* __restrict__ pb3, const float* __restrict__ bns,
    const float* __restrict__ pm, const float* __restrict__ pb,
    const float* __restrict__ new_xyz, const float* __restrict__ msa,
    float* __restrict__ out) {
  const int blk = blockIdx.x;  // 512
  const int b = blk >> 4, p0 = (blk & 15) * 16, t = threadIdx.x;
  // hand-packed LDS: Wt (l2 only) aliases X0/H (dead by l2)
  __shared__ __align__(16) char smem[58624];
  _Float16* X0h = (_Float16*)smem;             // 16*264*2 = 8448
  _Float16* X0l = (_Float16*)(smem + 8448);    // 8448
  _Float16* Hh  = (_Float16*)(smem + 16896);   // 8448
  _Float16* Hl  = (_Float16*)(smem + 25344);   // 8448 (ends 33792)
  float*    Wt  = (float*)smem;                // 256*20*4 = 20480 (alias)
  float*    Y2  = (float*)(smem + 33792);      // 16*260*4 = 16640
  float*    net_s = (float*)(smem + 50432);    // 16*120*4 = 7680

  {
#pragma unroll 4
    for (int s = 0; s < 16; s++) {
      const float v = y[(size_t)(b * P_ + p0 + s) * C_ + t];
      const _Float16 hi = (_Float16)v;
      X0h[s * 264 + t] = hi;
      X0l[s * 264 + t] = (_Float16)(v - (float)hi);
    }
  }
  const int lane = t & 63, w = t >> 6;
  const int m = lane & 15, q = lane >> 4;

  f32x4 acc[4];
  half8 pAh[4], pAl[4];
#pragma unroll
  for (int i = 0; i < 4; i++) {
    const int off = (((4 * w + i) * 8) * 64 + lane) * 8;
    pAh[i] = *(const half8*)&p1h[off];
    pAl[i] = *(const half8*)&p1l[off];
  }
  __syncthreads();

#pragma unroll
  for (int l = 0; l < 2; l++) {
    const _Float16* Xih = l ? Hh : X0h;
    const _Float16* Xil = l ? Hl : X0l;
#pragma unroll
    for (int i = 0; i < 4; i++) acc[i] = (f32x4){0.f, 0.f, 0.f, 0.f};
    for (int ks = 0; ks < 8; ks++) {
      half8 Ah[4], Al[4];
#pragma unroll
      for (int i = 0; i < 4; i++) { Ah[i] = pAh[i]; Al[i] = pAl[i]; }
      {
        int ln = l, kn = ks + 1;
        if (kn == 8) { ln = l + 1; kn = 0; }
        if (ln < 2) {
          const _Float16* Ph = ln ? p2h : p1h;
          const _Float16* Pl = ln ? p2l : p1l;
#pragma unroll
          for (int i = 0; i < 4; i++) {
            const int off = (((4 * w + i) * 8 + kn) * 64 + lane) * 8;
            pAh[i] = *(const half8*)&Ph[off];
            pAl[i] = *(const half8*)&Pl[off];
          }
        }
      }
      const int xo = ks * 32 + q * 8;
      const half8 Bh = *(const half8*)&Xih[m * 264 + xo];
      const half8 Bl = *(const half8*)&Xil[m * 264 + xo];
#pragma unroll
      for (int i = 0; i < 4; i++) {
        acc[i] = MFMA16(Ah[i], Bh, acc[i], 0, 0, 0);
        acc[i] = MFMA16(Ah[i], Bl, acc[i], 0, 0, 0);
        acc[i] = MFMA16(Al[i], Bh, acc[i], 0, 0, 0);
      }
    }
    // epilogue: BN + ReLU; l0 -> H (f16 split), l1 -> Y2 (f32)
#pragma unroll
    for (int i = 0; i < 4; i++) {
      const int ob = (4 * w + i) * 16 + q * 4;
      const f32x4 sc4 = *(const f32x4*)&bns[768 + l * 256 + ob];
      const f32x4 m4 = *(const f32x4*)&pm[l * 256 + ob];
      const f32x4 b4 = *(const f32x4*)&pb[l * 256 + ob];
      if (l == 0) {
        half4h vh, vl;
#pragma unroll
        for (int r = 0; r < 4; r++) {
          const float v = fmaxf((acc[i][r] - m4[r]) * sc4[r] + b4[r], 0.f);
          const _Float16 hi = (_Float16)v;
          vh[r] = hi;
          vl[r] = (_Float16)(v - (float)hi);
        }
        *(half4h*)&Hh[m * 264 + ob] = vh;
        *(half4h*)&Hl[m * 264 + ob] = vl;
      } else {
        f32x4 r4;
#pragma unroll
        for (int r = 0; r < 4; r++)
          r4[r] = fmaxf((acc[i][r] - m4[r]) * sc4[r] + b4[r], 0.f);
        *(f32x4*)&Y2[m * 260 + ob] = r4;
      }
    }
    __syncthreads();
  }

  // final layer (f32, round-7-exact): 119 outputs from Y2; Wt aliases X0/H
  {
    const int o = t & 127, ph = t >> 7;
    float a3[8];
#pragma unroll
    for (int pp = 0; pp < 8; pp++) a3[pp] = 0.f;
    for (int tile = 0; tile < 16; tile++) {
      const int c0 = tile * 16;
      for (int u = t; u < 119 * 4; u += 256) {
        int oo = u >> 2, qq = u & 3;
        *(float4*)&Wt[oo * 20 + qq * 4] =
            *(const float4*)(pw3 + oo * 256 + c0 + qq * 4);
      }
      __syncthreads();
      if (o < 119) {
#pragma unroll
        for (int j4 = 0; j4 < 4; j4++) {
          const float4 wv = *(const float4*)&Wt[o * 20 + j4 * 4];
#pragma unroll
          for (int pp = 0; pp < 8; pp++) {
            const float4 xv =
                *(const float4*)&Y2[(ph * 8 + pp) * 260 + c0 + j4 * 4];
            a3[pp] = fmaf(wv.x, xv.x, a3[pp]);
            a3[pp] = fmaf(wv.y, xv.y, a3[pp]);
            a3[pp] = fmaf(wv.z, xv.z, a3[pp]);
            a3[pp] = fmaf(wv.w, xv.w, a3[pp]);
          }
        }
      }
      __syncthreads();
    }
    if (o < 119) {
      const float bb = pb3[o];
#pragma unroll
      for (int pp = 0; pp < 8; pp++)
        net_s[(ph * 8 + pp) * 120 + o] = a3[pp] + bb;
    }
  }
  __syncthreads();

  if (t < 16) {
    const int gi = b * P_ + p0 + t;
    const float* nr = &net_s[t * 120];
    const float nx = new_xyz[gi * 3 + 0];
    const float ny = new_xyz[gi * 3 + 1];
    const float nz = new_xyz[gi * 3 + 2];
    const float obj0 = nr[0], obj1 = nr[1];
    out[OFF0 + gi * 2 + 0] = obj0;
    out[OFF0 + gi * 2 + 1] = obj1;
    const float cx = nx + nr[2], cy = ny + nr[3], cz = nz + nr[4];
    out[OFF1 + gi * 3 + 0] = cx;
    out[OFF1 + gi * 3 + 1] = cy;
    out[OFF1 + gi * 3 + 2] = cz;
    float bv = -1e30f;
    int bi = 0;
#pragma unroll
    for (int i = 0; i < 18; i++) {
      float v = nr[29 + i];
      out[OFF2 + gi * 18 + i] = v;
      if (v > bv) { bv = v; bi = i; }
    }
#pragma unroll
    for (int i = 0; i < 18; i++)
#pragma unroll
      for (int j = 0; j < 3; j++)
        out[OFF3 + gi * 54 + i * 3 + j] =
            __fmul_rn(nr[47 + i * 3 + j], msa[i * 3 + j]);
    float ps[3];
#pragma unroll
    for (int j = 0; j < 3; j++) {
      ps[j] = __fadd_rn(__fmul_rn(nr[47 + bi * 3 + j], msa[bi * 3 + j]),
                        msa[bi * 3 + j]);
      out[OFF4 + gi * 3 + j] = ps[j];
    }
    float sm = -1e30f;
#pragma unroll
    for (int i = 0; i < 18; i++) {
      float v = nr[101 + i];
      out[OFF5 + gi * 18 + i] = v;
      out[OFF7 + gi * 19 + i] = v;
      sm = fmaxf(sm, v);
    }
    out[OFF7 + gi * 19 + 18] = (obj0 <= obj1) ? 0.f : 1e10f;
    const float cc0 = cx, cc1 = cz, cc2 = -cy;
    const float sxk[8] = {1, 1, -1, -1, 1, 1, -1, -1};
    const float syk[8] = {1, 1, 1, 1, -1, -1, -1, -1};
    const float szk[8] = {1, -1, -1, 1, 1, -1, -1, 1};
#pragma unroll
    for (int k = 0; k < 8; k++) {
      out[OFF6 + gi * 24 + 3 * k + 0] = cc0 + ps[0] * sxk[k] * 0.5f;
      out[OFF6 + gi * 24 + 3 * k + 1] = cc1 + ps[2] * syk[k] * 0.5f;
      out[OFF6 + gi * 24 + 3 * k + 2] = cc2 + ps[1] * szk[k] * 0.5f;
    }
    {
      const float m2 = fmaxf(obj0, obj1);
      const float e0 = expf(obj0 - m2), e1 = expf(obj1 - m2);
      out[OFF8 + gi] = e1 / (e0 + e1);
    }
    {
      float ev[18], es = 0.f;
#pragma unroll
      for (int i = 0; i < 18; i++) {
        ev[i] = expf(nr[101 + i] - sm);
        es += ev[i];
      }
#pragma unroll
      for (int i = 0; i < 18; i++) out[OFF9 + gi * 18 + i] = ev[i] / es;
    }
  }
}

// ---------------------------------------------------------------------------
extern "C" void kernel_launch(void* const* d_in, const int* in_sizes, int n_in,
                              void* d_out, int out_size, void* d_ws,
                              size_t ws_size, hipStream_t stream) {
  (void)in_sizes; (void)n_in; (void)out_size; (void)ws_size;
  const float* xyz      = (const float*)d_in[0];
  const float* features = (const float*)d_in[1];
  const float* w1       = (const float*)d_in[2];
  const float* w2       = (const float*)d_in[3];
  const float* w3       = (const float*)d_in[4];
  const float* gma      = (const float*)d_in[5];
  const float* bta      = (const float*)d_in[6];
  const float* mu       = (const float*)d_in[7];
  const float* var      = (const float*)d_in[8];
  const float* pw1      = (const float*)d_in[9];
  const float* pw2      = (const float*)d_in[10];
  const float* pw3      = (const float*)d_in[11];
  const float* pb3      = (const float*)d_in[12];
  const float* pg       = (const float*)d_in[13];
  const float* pb       = (const float*)d_in[14];
  const float* pm       = (const float*)d_in[15];
  const float* pv       = (const float*)d_in[16];
  const float* msa      = (const float*)d_in[17];
  float* out = (float*)d_out;

  char* ws = (char*)d_ws;
  float*     new_xyz = (float*)ws;                   // 98304 B
  int*       idxw    = (int*)(ws + 98304);           // 524288 B
  float*     yb      = (float*)(ws + 622592);        // 8388608 B
  _Float16*  w1h     = (_Float16*)(ws + 9011200);    // 147456 B
  _Float16*  w1l     = (_Float16*)(ws + 9158656);    // 147456 B
  _Float16*  w2h     = (_Float16*)(ws + 9306112);    // 131072 B
  _Float16*  w2l     = (_Float16*)(ws + 9437184);    // 131072 B
  _Float16*  w3h     = (_Float16*)(ws + 9568256);    // 131072 B
  _Float16*  w3l     = (_Float16*)(ws + 9699328);    // 131072 B
  float*     bns     = (float*)(ws + 9830400);       // 5120 B (1280 f)
  _Float16*  p1h     = (_Float16*)(ws + 9835520);    // 131072 B
  _Float16*  p1l     = (_Float16*)(ws + 9966592);    // 131072 B
  _Float16*  p2h     = (_Float16*)(ws + 10097664);   // 131072 B
  _Float16*  p2l     = (_Float16*)(ws + 10228736);   // 131072 B -> 10359808

  // blocks 0..31: FPS (4 waves/batch); 32..196: wsplit x4 sub-blocks
  fused_pre_kernel<<<197, 256, 0, stream>>>(xyz, new_xyz, w1, w2, w3, pw1,
                                            pw2, gma, var, pg, pv, w1h, w1l,
                                            w2h, w2l, w3h, w3l, p1h, p1l, p2h,
                                            p2l, bns);
  ballq_kernel<<<B_, 256, 0, stream>>>(xyz, new_xyz, idxw);
  sa_kernel<<<B_ * 128, 512, 0, stream>>>(xyz, features, w1h, w1l, w2h, w2l,
                                          w3h, w3l, bns, mu, bta, new_xyz,
                                          idxw, yb);
  phead_kernel<<<B_ * 16, 256, 0, stream>>>(yb, p1h, p1l, p2h, p2l, pw3, pb3,
                                            bns, pm, pb, new_xyz, msa, out);
}

// Round 3
// 572.226 us; speedup vs baseline: 1.3545x; 1.1003x over previous
//
#include <hip/hip_runtime.h>
#include <math.h>

#define B_   32
#define K_   2048
#define C_   256
#define P_   256
#define S_   16
#define OUTC 119

// output offsets (floats)
#define OFF0 0        // obj        (B,P,2)
#define OFF1 16384    // center     (B,P,3)
#define OFF2 40960    // size_scores(B,P,18)
#define OFF3 188416   // size_res   (B,P,18,3)
#define OFF4 630784   // pred_size  (B,P,3)
#define OFF5 655360   // sem        (B,P,18)
#define OFF6 802816   // corners    (B,P,8,3)
#define OFF7 999424   // sem_logits (B,P,19)
#define OFF8 1155072  // obj_prob   (B,P)
#define OFF9 1163264  // sem_prob   (B,P,18)

typedef _Float16 half8  __attribute__((ext_vector_type(8)));
typedef _Float16 half4h __attribute__((ext_vector_type(4)));
typedef float    f32x4  __attribute__((ext_vector_type(4)));
#define MFMA16 __builtin_amdgcn_mfma_f32_16x16x32_f16

__device__ __forceinline__ float sqdist_rn(float ax, float ay, float az,
                                           float bx, float by, float bz) {
  float dx = __fsub_rn(ax, bx), dy = __fsub_rn(ay, by), dz = __fsub_rn(az, bz);
  return __fadd_rn(__fadd_rn(__fmul_rn(dx, dx), __fmul_rn(dy, dy)),
                   __fmul_rn(dz, dz));
}

__device__ __forceinline__ unsigned umax_(unsigned a, unsigned b) {
  return a > b ? a : b;
}
__device__ __forceinline__ unsigned umin_(unsigned a, unsigned b) {
  return a < b ? a : b;
}
// Wave64 u32 max via DPP (row_shr 1/2/4/8 + row_bcast15/31); result valid in
// lane 63. bound_ctrl=false -> invalid source lanes contribute `old`
// (identity). This is the LLVM AMDGPUAtomicOptimizer reduction pattern.
__device__ __forceinline__ unsigned wave_red_umax(unsigned x) {
  x = umax_(x, (unsigned)__builtin_amdgcn_update_dpp(0, (int)x, 0x111, 0xf, 0xf, false));
  x = umax_(x, (unsigned)__builtin_amdgcn_update_dpp(0, (int)x, 0x112, 0xf, 0xf, false));
  x = umax_(x, (unsigned)__builtin_amdgcn_update_dpp(0, (int)x, 0x114, 0xf, 0xf, false));
  x = umax_(x, (unsigned)__builtin_amdgcn_update_dpp(0, (int)x, 0x118, 0xf, 0xf, false));
  x = umax_(x, (unsigned)__builtin_amdgcn_update_dpp(0, (int)x, 0x142, 0xf, 0xf, false));
  x = umax_(x, (unsigned)__builtin_amdgcn_update_dpp(0, (int)x, 0x143, 0xf, 0xf, false));
  return x;
}
__device__ __forceinline__ unsigned wave_red_umin(unsigned x) {
  x = umin_(x, (unsigned)__builtin_amdgcn_update_dpp(-1, (int)x, 0x111, 0xf, 0xf, false));
  x = umin_(x, (unsigned)__builtin_amdgcn_update_dpp(-1, (int)x, 0x112, 0xf, 0xf, false));
  x = umin_(x, (unsigned)__builtin_amdgcn_update_dpp(-1, (int)x, 0x114, 0xf, 0xf, false));
  x = umin_(x, (unsigned)__builtin_amdgcn_update_dpp(-1, (int)x, 0x118, 0xf, 0xf, false));
  x = umin_(x, (unsigned)__builtin_amdgcn_update_dpp(-1, (int)x, 0x142, 0xf, 0xf, false));
  x = umin_(x, (unsigned)__builtin_amdgcn_update_dpp(-1, (int)x, 0x143, 0xf, 0xf, false));
  return x;
}

// ------------------------------------------- weight split to f16 hi/lo -----
// Fragment-order layout: Wf[tile = ot*nks + ks][lane][8] -> A-frag load is
// one coalesced 1KB wave read. sa l0 padded K 259->288 (9 k-steps).
// Sub-blocks: 0..143 w1, 144..271 w2, 272..399 w3, 400..527 pw1,
// 528..655 pw2, 656: BN scale prep. pw3 stays f32 (l2 exact).
__device__ __forceinline__ void wsplit_body(
    int r, int t, const float* __restrict__ w1, const float* __restrict__ w2,
    const float* __restrict__ w3, const float* __restrict__ pw1,
    const float* __restrict__ pw2, const float* __restrict__ gma,
    const float* __restrict__ var, const float* __restrict__ pg,
    const float* __restrict__ pv, _Float16* __restrict__ w1h,
    _Float16* __restrict__ w1l, _Float16* __restrict__ w2h,
    _Float16* __restrict__ w2l, _Float16* __restrict__ w3h,
    _Float16* __restrict__ w3l, _Float16* __restrict__ p1h,
    _Float16* __restrict__ p1l, _Float16* __restrict__ p2h,
    _Float16* __restrict__ p2l, float* __restrict__ bns) {
  if (r == 656) {
    for (int u = t; u < 768; u += 64) bns[u] = gma[u] / sqrtf(var[u] + 1e-5f);
    for (int u = t; u < 512; u += 64)
      bns[768 + u] = pg[u] / sqrtf(pv[u] + 1e-5f);
    return;
  }
  const float* src;
  _Float16 *dh, *dl;
  int ot, ks, nks, K;
  if (r < 144) {
    src = w1; dh = w1h; dl = w1l; ot = r / 9; ks = r % 9; nks = 9; K = 259;
  } else if (r < 272) {
    const int rr = r - 144;
    src = w2; dh = w2h; dl = w2l; ot = rr >> 3; ks = rr & 7; nks = 8; K = 256;
  } else if (r < 400) {
    const int rr = r - 272;
    src = w3; dh = w3h; dl = w3l; ot = rr >> 3; ks = rr & 7; nks = 8; K = 256;
  } else if (r < 528) {
    const int rr = r - 400;
    src = pw1; dh = p1h; dl = p1l; ot = rr >> 3; ks = rr & 7; nks = 8; K = 256;
  } else {
    const int rr = r - 528;
    src = pw2; dh = p2h; dl = p2l; ot = rr >> 3; ks = rr & 7; nks = 8; K = 256;
  }
  const int m = t & 15, q = t >> 4;
  const float* row = src + (ot * 16 + m) * K;
  half8 vh, vl;
#pragma unroll
  for (int j = 0; j < 8; j++) {
    const int c = ks * 32 + q * 8 + j;
    const float v = (c < K) ? row[c] : 0.f;
    const _Float16 hi = (_Float16)v;
    vh[j] = hi;
    vl[j] = (_Float16)(v - (float)hi);
  }
  const int base = ((ot * nks + ks) * 64 + t) * 8;
  *(half8*)&dh[base] = vh;
  *(half8*)&dl[base] = vl;
}

// ---------------------- fused FPS (4-wave) + wsplit + feature transpose ----
// Blocks 0..31: FPS (one per batch, 4 waves). Blocks 32..196: wsplit (4
// 64-thread sub-blocks each). Blocks 197..4292 (only when workspace fits):
// feature transpose (C,K)->(K,C) split-f16, 64x64 tiles via LDS (runs on the
// CUs FPS doesn't occupy -> ~free). Transposed layout makes the sa staging
// gather coalesced (512B contiguous per sample row vs 64 distinct cache
// lines per wave-instr in the (C,K) layout).
__global__ __launch_bounds__(256) void fused_pre_kernel(
    const float* __restrict__ xyz, float* __restrict__ new_xyz,
    const float* __restrict__ features, _Float16* __restrict__ ftH,
    _Float16* __restrict__ ftL,
    const float* __restrict__ w1, const float* __restrict__ w2,
    const float* __restrict__ w3, const float* __restrict__ pw1,
    const float* __restrict__ pw2, const float* __restrict__ gma,
    const float* __restrict__ var, const float* __restrict__ pg,
    const float* __restrict__ pv, _Float16* __restrict__ w1h,
    _Float16* __restrict__ w1l, _Float16* __restrict__ w2h,
    _Float16* __restrict__ w2l, _Float16* __restrict__ w3h,
    _Float16* __restrict__ w3l, _Float16* __restrict__ p1h,
    _Float16* __restrict__ p1l, _Float16* __restrict__ p2h,
    _Float16* __restrict__ p2l, float* __restrict__ bns) {
  __shared__ __align__(16) char smem_pre[32768];  // pts (fps) | tl (transpose)
  __shared__ uint2 redw[2][4];
  const int bid = blockIdx.x;

  if (bid >= 197) {
    // ---- feature transpose tile: 64 c x 64 k ----
    const int idx = bid - 197;                 // [0, 4096)
    const int b = idx >> 7, rem = idx & 127;
    const int c0 = (rem >> 5) * 64, k0 = (rem & 31) * 64;
    float* tl = (float*)smem_pre;              // [64][65]
    const int w = threadIdx.x >> 6, lane = threadIdx.x & 63;
    const float* fb = features + (size_t)b * C_ * K_;
#pragma unroll
    for (int r = 0; r < 16; r++) {
      const int cl = r * 4 + w;
      tl[cl * 65 + lane] = fb[(size_t)(c0 + cl) * K_ + k0 + lane];
    }
    __syncthreads();
#pragma unroll
    for (int r = 0; r < 16; r++) {
      const int kl = r * 4 + w;
      const float v = tl[lane * 65 + kl];
      const _Float16 hi = (_Float16)v;
      const size_t o = ((size_t)b * K_ + k0 + kl) * C_ + c0 + lane;
      ftH[o] = hi;
      ftL[o] = (_Float16)(v - (float)hi);
    }
    return;
  }

  if (bid >= 32) {
    const int sub = (bid - 32) * 4 + (threadIdx.x >> 6);
    if (sub < 657)
      wsplit_body(sub, threadIdx.x & 63, w1, w2, w3, pw1, pw2, gma, var, pg,
                  pv, w1h, w1l, w2h, w2l, w3h, w3l, p1h, p1l, p2h, p2l, bns);
    return;
  }

  // ---- FPS ----
  const int b = bid, t = threadIdx.x;
  const int lane = t & 63, w = t >> 6;
  float4* pts = (float4*)smem_pre;  // [K_]
  const float* xb = xyz + b * K_ * 3;
  float px[8], py[8], pz[8], dist[8];
#pragma unroll
  for (int j = 0; j < 8; j++) {
    const int k = t + 256 * j;
    const float x = xb[3 * k + 0];
    const float yv = xb[3 * k + 1];
    const float z = xb[3 * k + 2];
    px[j] = x; py[j] = yv; pz[j] = z;
    dist[j] = 1e10f;
    pts[k] = make_float4(x, yv, z, 0.f);
  }
  __syncthreads();
  int far = 0;
  for (int i = 0; i < P_; i++) {
    const float4 c = pts[far];  // uniform address -> LDS broadcast
    if (t == 0) {
      float* nx = new_xyz + (b * P_ + i) * 3;
      nx[0] = c.x; nx[1] = c.y; nx[2] = c.z;
    }
    float bv = -1.f;
    int bj = 0;
#pragma unroll
    for (int j = 0; j < 8; j++) {
      const float d = sqdist_rn(px[j], py[j], pz[j], c.x, c.y, c.z);
      dist[j] = fminf(dist[j], d);
      if (dist[j] > bv) { bv = dist[j]; bj = j; }  // strict > keeps lowest j
    }
    const unsigned bvb = __float_as_uint(bv);
    const unsigned gw = wave_red_umax(bvb);
    const unsigned gmaxw = (unsigned)__builtin_amdgcn_readlane((int)gw, 63);
    const unsigned kg = (unsigned)(bj * 256 + t);  // == global point index k
    const unsigned key2 = (bvb == gmaxw) ? kg : 0xFFFFFFFFu;
    const unsigned kw = wave_red_umin(key2);
    if (lane == 63) redw[i & 1][w] = make_uint2(gmaxw, kw);
    __syncthreads();
    const uint2 r0 = redw[i & 1][0], r1 = redw[i & 1][1];
    const uint2 r2 = redw[i & 1][2], r3 = redw[i & 1][3];
    const unsigned g = umax_(umax_(r0.x, r1.x), umax_(r2.x, r3.x));
    unsigned fk = 0xFFFFFFFFu;
    if (r0.x == g) fk = umin_(fk, r0.y);
    if (r1.x == g) fk = umin_(fk, r1.y);
    if (r2.x == g) fk = umin_(fk, r2.y);
    if (r3.x == g) fk = umin_(fk, r3.y);
    far = (int)fk;
  }
}

// ---------------------------------------------------------- ball query -----
__global__ __launch_bounds__(256) void ballq_kernel(const float* __restrict__ xyz,
                                                    const float* __restrict__ new_xyz,
                                                    int* __restrict__ idxw) {
  const int b = blockIdx.x, t = threadIdx.x;
  __shared__ __align__(16) float pts[K_ * 4];
  const float* xb = xyz + b * K_ * 3;
#pragma unroll
  for (int j = 0; j < 8; j++) {
    int k = t + 256 * j;
    pts[4 * k + 0] = xb[3 * k + 0];
    pts[4 * k + 1] = xb[3 * k + 1];
    pts[4 * k + 2] = xb[3 * k + 2];
    pts[4 * k + 3] = 0.f;
  }
  __syncthreads();
  const float r2 = (float)(0.3 * 0.3);
  const int p = t;
  const float nx = new_xyz[(b * P_ + p) * 3 + 0];
  const float ny = new_xyz[(b * P_ + p) * 3 + 1];
  const float nz = new_xyz[(b * P_ + p) * 3 + 2];
  int* ob = idxw + (b * P_ + p) * S_;
  int cnt = 0, first = 0;
  for (int k = 0; k < K_; k++) {
    if (cnt >= S_) break;
    const float4 q = *(const float4*)&pts[4 * k];
    float d2 = sqdist_rn(q.x, q.y, q.z, nx, ny, nz);
    if (d2 < r2) {
      if (cnt == 0) first = k;
      ob[cnt] = k;
      cnt++;
    }
  }
  for (int s = cnt; s < S_; s++) ob[s] = first;
}

// ------------------------------------------------------------- SA MLP ------
// Split-f16 MFMA: D = Wh*Xh + Wh*Xl + Wl*Xh (error ~2^-22). 2 proposals
// (32 samples)/block, 8 waves; wave w owns o-tiles {2w,2w+1}; depth-2
// weight-prefetch ring. ROUND-3 CHANGE: feature staging reads the
// pre-transposed split-f16 (K,C) arrays -> coalesced half8 loads (16B/lane,
// 512B contiguous per sample row) instead of 64-distinct-cache-line scalar
// gathers (theory: staging was L2-request-rate-bound, ~16k+ cyc per
// block-pair of TA serialization). Values bit-identical (same hi/lo split,
// same X column order); old gather kept as fallback when ws too small.
__global__ __launch_bounds__(512, 4) void sa_kernel(
    const float* __restrict__ xyz, const float* __restrict__ features,
    const _Float16* __restrict__ ftH, const _Float16* __restrict__ ftL,
    const int use_ft,
    const _Float16* __restrict__ w1h, const _Float16* __restrict__ w1l,
    const _Float16* __restrict__ w2h, const _Float16* __restrict__ w2l,
    const _Float16* __restrict__ w3h, const _Float16* __restrict__ w3l,
    const float* __restrict__ bns, const float* __restrict__ mu,
    const float* __restrict__ bta, const float* __restrict__ new_xyz,
    const int* __restrict__ idxw, float* __restrict__ y) {
  const int blk = blockIdx.x;  // 4096
  const int b = blk >> 7, p0 = (blk & 127) * 2, t = threadIdx.x;
  __shared__ __align__(16) _Float16 X1h[32 * 296];
  __shared__ __align__(16) _Float16 X1l[32 * 296];
  __shared__ __align__(16) _Float16 X2h[32 * 264];
  __shared__ __align__(16) _Float16 X2l[32 * 264];
  __shared__ __align__(16) float red[2 * 256];
  __shared__ int k_sh[32];

  if (t < 32) k_sh[t] = idxw[(b * P_ + p0) * S_ + t];
  for (int u = t; u < 32 * 32; u += 512) {
    const int s = u >> 5, cc = 256 + (u & 31);
    if (cc >= 259) {
      X1h[s * 296 + cc] = (_Float16)0.f;
      X1l[s * 296 + cc] = (_Float16)0.f;
    }
  }
  __syncthreads();
  if (t < 32) {
    const int pl = t >> 4, k = k_sh[t];
    const float* xb = xyz + b * K_ * 3;
    const float* nx = new_xyz + (b * P_ + p0 + pl) * 3;
#pragma unroll
    for (int c = 0; c < 3; c++) {
      const float v = (xb[3 * k + c] - nx[c]) / 0.3f;
      const _Float16 hi = (_Float16)v;
      X1h[t * 296 + c] = hi;
      X1l[t * 296 + c] = (_Float16)(v - (float)hi);
    }
  }
  if (use_ft) {
    // coalesced path: 1024 half8 chunks (32 samples x 32 chunks), 2/thread
    for (int u = t; u < 1024; u += 512) {
      const int s = u >> 5, ch = (u & 31) * 8;
      const size_t ro = ((size_t)b * K_ + k_sh[s]) * C_ + ch;
      const half8 vh = *(const half8*)&ftH[ro];
      const half8 vl = *(const half8*)&ftL[ro];
      // scalar stores (dest col 3+ch is 2B-aligned only); sequential banks
#pragma unroll
      for (int j = 0; j < 8; j++) {
        X1h[s * 296 + 3 + ch + j] = vh[j];
        X1l[s * 296 + 3 + ch + j] = vl[j];
      }
    }
  } else {
    // fallback: original (C,K) gather
    const int cl = t & 255, hf = t >> 8;
    const float* fb = features + (size_t)b * C_ * K_ + (size_t)cl * K_;
    const int c = 3 + cl;
    const int s0 = hf * 16;
#pragma unroll 8
    for (int s = s0; s < s0 + 16; s++) {
      const float v = fb[k_sh[s]];
      const _Float16 hi = (_Float16)v;
      X1h[s * 296 + c] = hi;
      X1l[s * 296 + c] = (_Float16)(v - (float)hi);
    }
  }

  const int lane = t & 63, w = t >> 6;  // w in 0..7
  const int m = lane & 15, q = lane >> 4;

  f32x4 acc[2][2];
  half8 rAh[2][2], rAl[2][2];  // [parity][i] depth-2 prefetch ring
#pragma unroll
  for (int i = 0; i < 2; i++) {
    rAh[0][i] = *(const half8*)&w1h[(((2 * w + i) * 9 + 0) * 64 + lane) * 8];
    rAl[0][i] = *(const half8*)&w1l[(((2 * w + i) * 9 + 0) * 64 + lane) * 8];
    rAh[1][i] = *(const half8*)&w1h[(((2 * w + i) * 9 + 1) * 64 + lane) * 8];
    rAl[1][i] = *(const half8*)&w1l[(((2 * w + i) * 9 + 1) * 64 + lane) * 8];
  }
  __syncthreads();

#pragma unroll
  for (int l = 0; l < 3; l++) {
    const _Float16* Xih = (l == 1) ? X2h : X1h;
    const _Float16* Xil = (l == 1) ? X2l : X1l;
    const int XS = (l == 1) ? 264 : 296;
    const int nks = (l == 0) ? 9 : 8;
    const int base = (l == 0) ? 0 : (l == 1) ? 9 : 17;  // flat step base
#pragma unroll
    for (int i = 0; i < 2; i++) {
      acc[i][0] = (f32x4){0.f, 0.f, 0.f, 0.f};
      acc[i][1] = (f32x4){0.f, 0.f, 0.f, 0.f};
    }
#pragma unroll
    for (int ks = 0; ks < nks; ks++) {
      const int par = (base + ks) & 1;  // compile-time under full unroll
      half8 Ah[2], Al[2];
#pragma unroll
      for (int i = 0; i < 2; i++) { Ah[i] = rAh[par][i]; Al[i] = rAl[par][i]; }
      {
        // prefetch flat-step + 2 into the parity slot just vacated
        int ln = l, kn = ks + 2;
        if (kn >= nks) { kn -= nks; ln = l + 1; }
        if (ln < 3) {
          const _Float16* Ph = (ln == 0) ? w1h : (ln == 1) ? w2h : w3h;
          const _Float16* Pl = (ln == 0) ? w1l : (ln == 1) ? w2l : w3l;
          const int nk2 = (ln == 0) ? 9 : 8;
#pragma unroll
          for (int i = 0; i < 2; i++) {
            const int off = (((2 * w + i) * nk2 + kn) * 64 + lane) * 8;
            rAh[par][i] = *(const half8*)&Ph[off];
            rAl[par][i] = *(const half8*)&Pl[off];
          }
        }
      }
      const int xo = ks * 32 + q * 8;
      const half8 Bh0 = *(const half8*)&Xih[m * XS + xo];
      const half8 Bl0 = *(const half8*)&Xil[m * XS + xo];
      const half8 Bh1 = *(const half8*)&Xih[(16 + m) * XS + xo];
      const half8 Bl1 = *(const half8*)&Xil[(16 + m) * XS + xo];
#pragma unroll
      for (int i = 0; i < 2; i++) {
        acc[i][0] = MFMA16(Ah[i], Bh0, acc[i][0], 0, 0, 0);
        acc[i][0] = MFMA16(Ah[i], Bl0, acc[i][0], 0, 0, 0);
        acc[i][0] = MFMA16(Al[i], Bh0, acc[i][0], 0, 0, 0);
        acc[i][1] = MFMA16(Ah[i], Bh1, acc[i][1], 0, 0, 0);
        acc[i][1] = MFMA16(Ah[i], Bl1, acc[i][1], 0, 0, 0);
        acc[i][1] = MFMA16(Al[i], Bh1, acc[i][1], 0, 0, 0);
      }
    }

    if (l < 2) {
      _Float16* Xoh = (l == 0) ? X2h : X1h;
      _Float16* Xol = (l == 0) ? X2l : X1l;
      const int XSo = (l == 0) ? 264 : 296;
#pragma unroll
      for (int i = 0; i < 2; i++) {
        const int ob = (2 * w + i) * 16 + q * 4;
        const f32x4 sc4 = *(const f32x4*)&bns[l * 256 + ob];
        const f32x4 m4 = *(const f32x4*)&mu[l * 256 + ob];
        const f32x4 b4 = *(const f32x4*)&bta[l * 256 + ob];
#pragma unroll
        for (int s = 0; s < 2; s++) {
          half4h vh, vl;
#pragma unroll
          for (int r = 0; r < 4; r++) {
            const float v = fmaxf((acc[i][s][r] - m4[r]) * sc4[r] + b4[r], 0.f);
            const _Float16 hi = (_Float16)v;
            vh[r] = hi;
            vl[r] = (_Float16)(v - (float)hi);
          }
          const int scol = s * 16 + m;
          *(half4h*)&Xoh[scol * XSo + ob] = vh;
          *(half4h*)&Xol[scol * XSo + ob] = vl;
        }
      }
      __syncthreads();
    } else {
#pragma unroll
      for (int i = 0; i < 2; i++)
#pragma unroll
        for (int s = 0; s < 2; s++)
#pragma unroll
          for (int r = 0; r < 4; r++) {
            float v = acc[i][s][r];
            v = fmaxf(v, __shfl_xor(v, 1));
            v = fmaxf(v, __shfl_xor(v, 2));
            v = fmaxf(v, __shfl_xor(v, 4));
            v = fmaxf(v, __shfl_xor(v, 8));
            acc[i][s][r] = v;
          }
      if (m == 0) {
#pragma unroll
        for (int i = 0; i < 2; i++) {
          const int ob = (2 * w + i) * 16 + q * 4;
          *(f32x4*)&red[ob] = acc[i][0];
          *(f32x4*)&red[256 + ob] = acc[i][1];
        }
      }
      __syncthreads();
      // 512 threads cover the 2x256 outputs in one shot
      const int pl = t >> 8, col = t & 255;
      const float sc2 = bns[512 + col];
      const float mu2 = mu[512 + col], bt2 = bta[512 + col];
      const float raw = red[pl * 256 + col];
      y[(b * P_ + p0 + pl) * 256 + col] = fmaxf((raw - mu2) * sc2 + bt2, 0.f);
    }
  }
}

// ------------------------------------------------- P-layers + all heads ----
// l0/l1: split-f16 MFMA (sa-proven; noise enters obj only through 2 BN+ReLU
// layers). l2 (obj-producing 119x256): EXACT round-7 f32 path, reading f32
// Y2 — no direct perturbation on argmin(obj). Round-6 bug (net_s stride 124
// vs ob<=127 collision) eliminated: l2 writes only o<119, stride 120.
__global__ __launch_bounds__(256, 2) void phead_kernel(
    const float* __restrict__ y, const _Float16* __restrict__ p1h,
    const _Float16* __restrict__ p1l, const _Float16* __restrict__ p2h,
    const _Float16* __restrict__ p2l, const float* __restrict__ pw3,
    const float* __restrict__ pb3, const float* __restrict__ bns,
    const float* __restrict__ pm, const float* __restrict__ pb,
    const float* __restrict__ new_xyz, const float* __restrict__ msa,
    float* __restrict__ out) {
  const int blk = blockIdx.x;  // 512
  const int b = blk >> 4, p0 = (blk & 15) * 16, t = threadIdx.x;
  // hand-packed LDS: Wt (l2 only) aliases X0/H (dead by l2)
  __shared__ __align__(16) char smem[58624];
  _Float16* X0h = (_Float16*)smem;             // 16*264*2 = 8448
  _Float16* X0l = (_Float16*)(smem + 8448);    // 8448
  _Float16* Hh  = (_Float16*)(smem + 16896);   // 8448
  _Float16* Hl  = (_Float16*)(smem + 25344);   // 8448 (ends 33792)
  float*    Wt  = (float*)smem;                // 256*20*4 = 20480 (alias)
  float*    Y2  = (float*)(smem + 33792);      // 16*260*4 = 16640
  float*    net_s = (float*)(smem + 50432);    // 16*120*4 = 7680

  {
#pragma unroll 4
    for (int s = 0; s < 16; s++) {
      const float v = y[(size_t)(b * P_ + p0 + s) * C_ + t];
      const _Float16 hi = (_Float16)v;
      X0h[s * 264 + t] = hi;
      X0l[s * 264 + t] = (_Float16)(v - (float)hi);
    }
  }
  const int lane = t & 63, w = t >> 6;
  const int m = lane & 15, q = lane >> 4;

  f32x4 acc[4];
  half8 pAh[4], pAl[4];
#pragma unroll
  for (int i = 0; i < 4; i++) {
    const int off = (((4 * w + i) * 8) * 64 + lane) * 8;
    pAh[i] = *(const half8*)&p1h[off];
    pAl[i] = *(const half8*)&p1l[off];
  }
  __syncthreads();

#pragma unroll
  for (int l = 0; l < 2; l++) {
    const _Float16* Xih = l ? Hh : X0h;
    const _Float16* Xil = l ? Hl : X0l;
#pragma unroll
    for (int i = 0; i < 4; i++) acc[i] = (f32x4){0.f, 0.f, 0.f, 0.f};
    for (int ks = 0; ks < 8; ks++) {
      half8 Ah[4], Al[4];
#pragma unroll
      for (int i = 0; i < 4; i++) { Ah[i] = pAh[i]; Al[i] = pAl[i]; }
      {
        int ln = l, kn = ks + 1;
        if (kn == 8) { ln = l + 1; kn = 0; }
        if (ln < 2) {
          const _Float16* Ph = ln ? p2h : p1h;
          const _Float16* Pl = ln ? p2l : p1l;
#pragma unroll
          for (int i = 0; i < 4; i++) {
            const int off = (((4 * w + i) * 8 + kn) * 64 + lane) * 8;
            pAh[i] = *(const half8*)&Ph[off];
            pAl[i] = *(const half8*)&Pl[off];
          }
        }
      }
      const int xo = ks * 32 + q * 8;
      const half8 Bh = *(const half8*)&Xih[m * 264 + xo];
      const half8 Bl = *(const half8*)&Xil[m * 264 + xo];
#pragma unroll
      for (int i = 0; i < 4; i++) {
        acc[i] = MFMA16(Ah[i], Bh, acc[i], 0, 0, 0);
        acc[i] = MFMA16(Ah[i], Bl, acc[i], 0, 0, 0);
        acc[i] = MFMA16(Al[i], Bh, acc[i], 0, 0, 0);
      }
    }
    // epilogue: BN + ReLU; l0 -> H (f16 split), l1 -> Y2 (f32)
#pragma unroll
    for (int i = 0; i < 4; i++) {
      const int ob = (4 * w + i) * 16 + q * 4;
      const f32x4 sc4 = *(const f32x4*)&bns[768 + l * 256 + ob];
      const f32x4 m4 = *(const f32x4*)&pm[l * 256 + ob];
      const f32x4 b4 = *(const f32x4*)&pb[l * 256 + ob];
      if (l == 0) {
        half4h vh, vl;
#pragma unroll
        for (int r = 0; r < 4; r++) {
          const float v = fmaxf((acc[i][r] - m4[r]) * sc4[r] + b4[r], 0.f);
          const _Float16 hi = (_Float16)v;
          vh[r] = hi;
          vl[r] = (_Float16)(v - (float)hi);
        }
        *(half4h*)&Hh[m * 264 + ob] = vh;
        *(half4h*)&Hl[m * 264 + ob] = vl;
      } else {
        f32x4 r4;
#pragma unroll
        for (int r = 0; r < 4; r++)
          r4[r] = fmaxf((acc[i][r] - m4[r]) * sc4[r] + b4[r], 0.f);
        *(f32x4*)&Y2[m * 260 + ob] = r4;
      }
    }
    __syncthreads();
  }

  // final layer (f32, round-7-exact): 119 outputs from Y2; Wt aliases X0/H
  {
    const int o = t & 127, ph = t >> 7;
    float a3[8];
#pragma unroll
    for (int pp = 0; pp < 8; pp++) a3[pp] = 0.f;
    for (int tile = 0; tile < 16; tile++) {
      const int c0 = tile * 16;
      for (int u = t; u < 119 * 4; u += 256) {
        int oo = u >> 2, qq = u & 3;
        *(float4*)&Wt[oo * 20 + qq * 4] =
            *(const float4*)(pw3 + oo * 256 + c0 + qq * 4);
      }
      __syncthreads();
      if (o < 119) {
#pragma unroll
        for (int j4 = 0; j4 < 4; j4++) {
          const float4 wv = *(const float4*)&Wt[o * 20 + j4 * 4];
#pragma unroll
          for (int pp = 0; pp < 8; pp++) {
            const float4 xv =
                *(const float4*)&Y2[(ph * 8 + pp) * 260 + c0 + j4 * 4];
            a3[pp] = fmaf(wv.x, xv.x, a3[pp]);
            a3[pp] = fmaf(wv.y, xv.y, a3[pp]);
            a3[pp] = fmaf(wv.z, xv.z, a3[pp]);
            a3[pp] = fmaf(wv.w, xv.w, a3[pp]);
          }
        }
      }
      __syncthreads();
    }
    if (o < 119) {
      const float bb = pb3[o];
#pragma unroll
      for (int pp = 0; pp < 8; pp++)
        net_s[(ph * 8 + pp) * 120 + o] = a3[pp] + bb;
    }
  }
  __syncthreads();

  if (t < 16) {
    const int gi = b * P_ + p0 + t;
    const float* nr = &net_s[t * 120];
    const float nx = new_xyz[gi * 3 + 0];
    const float ny = new_xyz[gi * 3 + 1];
    const float nz = new_xyz[gi * 3 + 2];
    const float obj0 = nr[0], obj1 = nr[1];
    out[OFF0 + gi * 2 + 0] = obj0;
    out[OFF0 + gi * 2 + 1] = obj1;
    const float cx = nx + nr[2], cy = ny + nr[3], cz = nz + nr[4];
    out[OFF1 + gi * 3 + 0] = cx;
    out[OFF1 + gi * 3 + 1] = cy;
    out[OFF1 + gi * 3 + 2] = cz;
    float bv = -1e30f;
    int bi = 0;
#pragma unroll
    for (int i = 0; i < 18; i++) {
      float v = nr[29 + i];
      out[OFF2 + gi * 18 + i] = v;
      if (v > bv) { bv = v; bi = i; }
    }
#pragma unroll
    for (int i = 0; i < 18; i++)
#pragma unroll
      for (int j = 0; j < 3; j++)
        out[OFF3 + gi * 54 + i * 3 + j] =
            __fmul_rn(nr[47 + i * 3 + j], msa[i * 3 + j]);
    float ps[3];
#pragma unroll
    for (int j = 0; j < 3; j++) {
      ps[j] = __fadd_rn(__fmul_rn(nr[47 + bi * 3 + j], msa[bi * 3 + j]),
                        msa[bi * 3 + j]);
      out[OFF4 + gi * 3 + j] = ps[j];
    }
    float sm = -1e30f;
#pragma unroll
    for (int i = 0; i < 18; i++) {
      float v = nr[101 + i];
      out[OFF5 + gi * 18 + i] = v;
      out[OFF7 + gi * 19 + i] = v;
      sm = fmaxf(sm, v);
    }
    out[OFF7 + gi * 19 + 18] = (obj0 <= obj1) ? 0.f : 1e10f;
    const float cc0 = cx, cc1 = cz, cc2 = -cy;
    const float sxk[8] = {1, 1, -1, -1, 1, 1, -1, -1};
    const float syk[8] = {1, 1, 1, 1, -1, -1, -1, -1};
    const float szk[8] = {1, -1, -1, 1, 1, -1, -1, 1};
#pragma unroll
    for (int k = 0; k < 8; k++) {
      out[OFF6 + gi * 24 + 3 * k + 0] = cc0 + ps[0] * sxk[k] * 0.5f;
      out[OFF6 + gi * 24 + 3 * k + 1] = cc1 + ps[2] * syk[k] * 0.5f;
      out[OFF6 + gi * 24 + 3 * k + 2] = cc2 + ps[1] * szk[k] * 0.5f;
    }
    {
      const float m2 = fmaxf(obj0, obj1);
      const float e0 = expf(obj0 - m2), e1 = expf(obj1 - m2);
      out[OFF8 + gi] = e1 / (e0 + e1);
    }
    {
      float ev[18], es = 0.f;
#pragma unroll
      for (int i = 0; i < 18; i++) {
        ev[i] = expf(nr[101 + i] - sm);
        es += ev[i];
      }
#pragma unroll
      for (int i = 0; i < 18; i++) out[OFF9 + gi * 18 + i] = ev[i] / es;
    }
  }
}

// ---------------------------------------------------------------------------
extern "C" void kernel_launch(void* const* d_in, const int* in_sizes, int n_in,
                              void* d_out, int out_size, void* d_ws,
                              size_t ws_size, hipStream_t stream) {
  (void)in_sizes; (void)n_in; (void)out_size;
  const float* xyz      = (const float*)d_in[0];
  const float* features = (const float*)d_in[1];
  const float* w1       = (const float*)d_in[2];
  const float* w2       = (const float*)d_in[3];
  const float* w3       = (const float*)d_in[4];
  const float* gma      = (const float*)d_in[5];
  const float* bta      = (const float*)d_in[6];
  const float* mu       = (const float*)d_in[7];
  const float* var      = (const float*)d_in[8];
  const float* pw1      = (const float*)d_in[9];
  const float* pw2      = (const float*)d_in[10];
  const float* pw3      = (const float*)d_in[11];
  const float* pb3      = (const float*)d_in[12];
  const float* pg       = (const float*)d_in[13];
  const float* pb       = (const float*)d_in[14];
  const float* pm       = (const float*)d_in[15];
  const float* pv       = (const float*)d_in[16];
  const float* msa      = (const float*)d_in[17];
  float* out = (float*)d_out;

  char* ws = (char*)d_ws;
  float*     new_xyz = (float*)ws;                   // 98304 B
  int*       idxw    = (int*)(ws + 98304);           // 524288 B
  float*     yb      = (float*)(ws + 622592);        // 8388608 B
  _Float16*  w1h     = (_Float16*)(ws + 9011200);    // 147456 B
  _Float16*  w1l     = (_Float16*)(ws + 9158656);    // 147456 B
  _Float16*  w2h     = (_Float16*)(ws + 9306112);    // 131072 B
  _Float16*  w2l     = (_Float16*)(ws + 9437184);    // 131072 B
  _Float16*  w3h     = (_Float16*)(ws + 9568256);    // 131072 B
  _Float16*  w3l     = (_Float16*)(ws + 9699328);    // 131072 B
  float*     bns     = (float*)(ws + 9830400);       // 5120 B (1280 f)
  _Float16*  p1h     = (_Float16*)(ws + 9835520);    // 131072 B
  _Float16*  p1l     = (_Float16*)(ws + 9966592);    // 131072 B
  _Float16*  p2h     = (_Float16*)(ws + 10097664);   // 131072 B
  _Float16*  p2l     = (_Float16*)(ws + 10228736);   // 131072 B -> 10359808
  _Float16*  ftH     = (_Float16*)(ws + 10359808);   // 33554432 B
  _Float16*  ftL     = (_Float16*)(ws + 43914240);   // 33554432 B -> 77468672

  const int use_ft = (ws_size >= 77468672ull) ? 1 : 0;
  const int npre = use_ft ? (197 + 4096) : 197;

  // blocks 0..31: FPS; 32..196: wsplit x4; 197..4292: feature transpose
  fused_pre_kernel<<<npre, 256, 0, stream>>>(xyz, new_xyz, features, ftH, ftL,
                                             w1, w2, w3, pw1, pw2, gma, var,
                                             pg, pv, w1h, w1l, w2h, w2l, w3h,
                                             w3l, p1h, p1l, p2h, p2l, bns);
  ballq_kernel<<<B_, 256, 0, stream>>>(xyz, new_xyz, idxw);
  sa_kernel<<<B_ * 128, 512, 0, stream>>>(xyz, features, ftH, ftL, use_ft,
                                          w1h, w1l, w2h, w2l, w3h, w3l, bns,
                                          mu, bta, new_xyz, idxw, yb);
  phead_kernel<<<B_ * 16, 256, 0, stream>>>(yb, p1h, p1l, p2h, p2l, pw3, pb3,
                                            bns, pm, pb, new_xyz, msa, out);
}

// Round 4
// 449.254 us; speedup vs baseline: 1.7253x; 1.2737x over previous
//
#include <hip/hip_runtime.h>
#include <math.h>

#define B_   32
#define K_   2048
#define C_   256
#define P_   256
#define S_   16
#define OUTC 119

// output offsets (floats)
#define OFF0 0        // obj        (B,P,2)
#define OFF1 16384    // center     (B,P,3)
#define OFF2 40960    // size_scores(B,P,18)
#define OFF3 188416   // size_res   (B,P,18,3)
#define OFF4 630784   // pred_size  (B,P,3)
#define OFF5 655360   // sem        (B,P,18)
#define OFF6 802816   // corners    (B,P,8,3)
#define OFF7 999424   // sem_logits (B,P,19)
#define OFF8 1155072  // obj_prob   (B,P)
#define OFF9 1163264  // sem_prob   (B,P,18)

typedef _Float16 half8  __attribute__((ext_vector_type(8)));
typedef _Float16 half4h __attribute__((ext_vector_type(4)));
typedef float    f32x4  __attribute__((ext_vector_type(4)));
#define MFMA16 __builtin_amdgcn_mfma_f32_16x16x32_f16

__device__ __forceinline__ float sqdist_rn(float ax, float ay, float az,
                                           float bx, float by, float bz) {
  float dx = __fsub_rn(ax, bx), dy = __fsub_rn(ay, by), dz = __fsub_rn(az, bz);
  return __fadd_rn(__fadd_rn(__fmul_rn(dx, dx), __fmul_rn(dy, dy)),
                   __fmul_rn(dz, dz));
}

__device__ __forceinline__ unsigned umax_(unsigned a, unsigned b) {
  return a > b ? a : b;
}
__device__ __forceinline__ unsigned umin_(unsigned a, unsigned b) {
  return a < b ? a : b;
}
// Wave64 u32 max via DPP (row_shr 1/2/4/8 + row_bcast15/31); result valid in
// lane 63. bound_ctrl=false -> invalid source lanes contribute `old`
// (identity). This is the LLVM AMDGPUAtomicOptimizer reduction pattern.
__device__ __forceinline__ unsigned wave_red_umax(unsigned x) {
  x = umax_(x, (unsigned)__builtin_amdgcn_update_dpp(0, (int)x, 0x111, 0xf, 0xf, false));
  x = umax_(x, (unsigned)__builtin_amdgcn_update_dpp(0, (int)x, 0x112, 0xf, 0xf, false));
  x = umax_(x, (unsigned)__builtin_amdgcn_update_dpp(0, (int)x, 0x114, 0xf, 0xf, false));
  x = umax_(x, (unsigned)__builtin_amdgcn_update_dpp(0, (int)x, 0x118, 0xf, 0xf, false));
  x = umax_(x, (unsigned)__builtin_amdgcn_update_dpp(0, (int)x, 0x142, 0xf, 0xf, false));
  x = umax_(x, (unsigned)__builtin_amdgcn_update_dpp(0, (int)x, 0x143, 0xf, 0xf, false));
  return x;
}
__device__ __forceinline__ unsigned wave_red_umin(unsigned x) {
  x = umin_(x, (unsigned)__builtin_amdgcn_update_dpp(-1, (int)x, 0x111, 0xf, 0xf, false));
  x = umin_(x, (unsigned)__builtin_amdgcn_update_dpp(-1, (int)x, 0x112, 0xf, 0xf, false));
  x = umin_(x, (unsigned)__builtin_amdgcn_update_dpp(-1, (int)x, 0x114, 0xf, 0xf, false));
  x = umin_(x, (unsigned)__builtin_amdgcn_update_dpp(-1, (int)x, 0x118, 0xf, 0xf, false));
  x = umin_(x, (unsigned)__builtin_amdgcn_update_dpp(-1, (int)x, 0x142, 0xf, 0xf, false));
  x = umin_(x, (unsigned)__builtin_amdgcn_update_dpp(-1, (int)x, 0x143, 0xf, 0xf, false));
  return x;
}

// ------------------------------------------- weight split to f16 hi/lo -----
// Fragment-order layout: Wf[tile = ot*nks + ks][lane][8] -> A-frag load is
// one coalesced 1KB wave read. ROUND-4: w1 columns remapped to octet-aligned
// X layout: dest c 0..2 = xyz (src 0..2), c 3..7 = zero, c 8..263 =
// features (src 3..258), c>=264 zero. Same dot products, k-grouping shifts.
__device__ __forceinline__ void wsplit_body(
    int r, int t, const float* __restrict__ w1, const float* __restrict__ w2,
    const float* __restrict__ w3, const float* __restrict__ pw1,
    const float* __restrict__ pw2, const float* __restrict__ gma,
    const float* __restrict__ var, const float* __restrict__ pg,
    const float* __restrict__ pv, _Float16* __restrict__ w1h,
    _Float16* __restrict__ w1l, _Float16* __restrict__ w2h,
    _Float16* __restrict__ w2l, _Float16* __restrict__ w3h,
    _Float16* __restrict__ w3l, _Float16* __restrict__ p1h,
    _Float16* __restrict__ p1l, _Float16* __restrict__ p2h,
    _Float16* __restrict__ p2l, float* __restrict__ bns) {
  if (r == 656) {
    for (int u = t; u < 768; u += 64) bns[u] = gma[u] / sqrtf(var[u] + 1e-5f);
    for (int u = t; u < 512; u += 64)
      bns[768 + u] = pg[u] / sqrtf(pv[u] + 1e-5f);
    return;
  }
  const float* src;
  _Float16 *dh, *dl;
  int ot, ks, nks, K, remap = 0;
  if (r < 144) {
    src = w1; dh = w1h; dl = w1l; ot = r / 9; ks = r % 9; nks = 9; K = 259;
    remap = 1;
  } else if (r < 272) {
    const int rr = r - 144;
    src = w2; dh = w2h; dl = w2l; ot = rr >> 3; ks = rr & 7; nks = 8; K = 256;
  } else if (r < 400) {
    const int rr = r - 272;
    src = w3; dh = w3h; dl = w3l; ot = rr >> 3; ks = rr & 7; nks = 8; K = 256;
  } else if (r < 528) {
    const int rr = r - 400;
    src = pw1; dh = p1h; dl = p1l; ot = rr >> 3; ks = rr & 7; nks = 8; K = 256;
  } else {
    const int rr = r - 528;
    src = pw2; dh = p2h; dl = p2l; ot = rr >> 3; ks = rr & 7; nks = 8; K = 256;
  }
  const int m = t & 15, q = t >> 4;
  const float* row = src + (ot * 16 + m) * K;
  half8 vh, vl;
#pragma unroll
  for (int j = 0; j < 8; j++) {
    const int c = ks * 32 + q * 8 + j;
    float v;
    if (remap) {
      v = (c < 3) ? row[c] : (c >= 8 && c < 264) ? row[c - 5] : 0.f;
    } else {
      v = (c < K) ? row[c] : 0.f;
    }
    const _Float16 hi = (_Float16)v;
    vh[j] = hi;
    vl[j] = (_Float16)(v - (float)hi);
  }
  const int base = ((ot * nks + ks) * 64 + t) * 8;
  *(half8*)&dh[base] = vh;
  *(half8*)&dl[base] = vl;
}

// ---------------------- fused FPS (4-wave) + wsplit + feature transpose ----
// Blocks 0..31: FPS (one per batch, 4 waves). Blocks 32..196: wsplit (4
// 64-thread sub-blocks each). Blocks 197..4292: feature transpose
// (C,K)->(K,C) split-f16, 64x64 tiles via LDS.
__global__ __launch_bounds__(256) void fused_pre_kernel(
    const float* __restrict__ xyz, float* __restrict__ new_xyz,
    const float* __restrict__ features, _Float16* __restrict__ ftH,
    _Float16* __restrict__ ftL,
    const float* __restrict__ w1, const float* __restrict__ w2,
    const float* __restrict__ w3, const float* __restrict__ pw1,
    const float* __restrict__ pw2, const float* __restrict__ gma,
    const float* __restrict__ var, const float* __restrict__ pg,
    const float* __restrict__ pv, _Float16* __restrict__ w1h,
    _Float16* __restrict__ w1l, _Float16* __restrict__ w2h,
    _Float16* __restrict__ w2l, _Float16* __restrict__ w3h,
    _Float16* __restrict__ w3l, _Float16* __restrict__ p1h,
    _Float16* __restrict__ p1l, _Float16* __restrict__ p2h,
    _Float16* __restrict__ p2l, float* __restrict__ bns) {
  __shared__ __align__(16) char smem_pre[32768];  // pts (fps) | tl (transpose)
  __shared__ uint2 redw[2][4];
  const int bid = blockIdx.x;

  if (bid >= 197) {
    // ---- feature transpose tile: 64 c x 64 k ----
    const int idx = bid - 197;                 // [0, 4096)
    const int b = idx >> 7, rem = idx & 127;
    const int c0 = (rem >> 5) * 64, k0 = (rem & 31) * 64;
    float* tl = (float*)smem_pre;              // [64][65]
    const int w = threadIdx.x >> 6, lane = threadIdx.x & 63;
    const float* fb = features + (size_t)b * C_ * K_;
#pragma unroll
    for (int r = 0; r < 16; r++) {
      const int cl = r * 4 + w;
      tl[cl * 65 + lane] = fb[(size_t)(c0 + cl) * K_ + k0 + lane];
    }
    __syncthreads();
#pragma unroll
    for (int r = 0; r < 16; r++) {
      const int kl = r * 4 + w;
      const float v = tl[lane * 65 + kl];
      const _Float16 hi = (_Float16)v;
      const size_t o = ((size_t)b * K_ + k0 + kl) * C_ + c0 + lane;
      ftH[o] = hi;
      ftL[o] = (_Float16)(v - (float)hi);
    }
    return;
  }

  if (bid >= 32) {
    const int sub = (bid - 32) * 4 + (threadIdx.x >> 6);
    if (sub < 657)
      wsplit_body(sub, threadIdx.x & 63, w1, w2, w3, pw1, pw2, gma, var, pg,
                  pv, w1h, w1l, w2h, w2l, w3h, w3l, p1h, p1l, p2h, p2l, bns);
    return;
  }

  // ---- FPS ----
  const int b = bid, t = threadIdx.x;
  const int lane = t & 63, w = t >> 6;
  float4* pts = (float4*)smem_pre;  // [K_]
  const float* xb = xyz + b * K_ * 3;
  float px[8], py[8], pz[8], dist[8];
#pragma unroll
  for (int j = 0; j < 8; j++) {
    const int k = t + 256 * j;
    const float x = xb[3 * k + 0];
    const float yv = xb[3 * k + 1];
    const float z = xb[3 * k + 2];
    px[j] = x; py[j] = yv; pz[j] = z;
    dist[j] = 1e10f;
    pts[k] = make_float4(x, yv, z, 0.f);
  }
  __syncthreads();
  int far = 0;
  for (int i = 0; i < P_; i++) {
    const float4 c = pts[far];  // uniform address -> LDS broadcast
    if (t == 0) {
      float* nx = new_xyz + (b * P_ + i) * 3;
      nx[0] = c.x; nx[1] = c.y; nx[2] = c.z;
    }
    float bv = -1.f;
    int bj = 0;
#pragma unroll
    for (int j = 0; j < 8; j++) {
      const float d = sqdist_rn(px[j], py[j], pz[j], c.x, c.y, c.z);
      dist[j] = fminf(dist[j], d);
      if (dist[j] > bv) { bv = dist[j]; bj = j; }  // strict > keeps lowest j
    }
    const unsigned bvb = __float_as_uint(bv);
    const unsigned gw = wave_red_umax(bvb);
    const unsigned gmaxw = (unsigned)__builtin_amdgcn_readlane((int)gw, 63);
    const unsigned kg = (unsigned)(bj * 256 + t);  // == global point index k
    const unsigned key2 = (bvb == gmaxw) ? kg : 0xFFFFFFFFu;
    const unsigned kw = wave_red_umin(key2);
    if (lane == 63) redw[i & 1][w] = make_uint2(gmaxw, kw);
    __syncthreads();
    const uint2 r0 = redw[i & 1][0], r1 = redw[i & 1][1];
    const uint2 r2 = redw[i & 1][2], r3 = redw[i & 1][3];
    const unsigned g = umax_(umax_(r0.x, r1.x), umax_(r2.x, r3.x));
    unsigned fk = 0xFFFFFFFFu;
    if (r0.x == g) fk = umin_(fk, r0.y);
    if (r1.x == g) fk = umin_(fk, r1.y);
    if (r2.x == g) fk = umin_(fk, r2.y);
    if (r3.x == g) fk = umin_(fk, r3.y);
    far = (int)fk;
  }
}

// ---------------------------------------------------------- ball query -----
// ROUND-4 rewrite: one WAVE per proposal (was: one thread, serial scan with
// break -> ~130cy/iter dependent LDS chain x up to 2048 iters on 32 blocks).
// Lane l tests k = j*64+l for j=0..31 (canonical conflict-free LDS reads),
// builds a 32-bit hit mask, then ballot+popcount-prefix emits the first 16
// hits in exact ascending-k order (identical semantics incl. `first` pad).
__global__ __launch_bounds__(1024) void ballq_kernel(
    const float* __restrict__ xyz, const float* __restrict__ new_xyz,
    int* __restrict__ idxw) {
  const int blk = blockIdx.x;  // 512 = 32 batches x 16 groups
  const int b = blk >> 4, pg = (blk & 15) * 16, t = threadIdx.x;
  __shared__ __align__(16) float4 pts[K_];  // 32 KB
  const float* xb = xyz + b * K_ * 3;
#pragma unroll
  for (int j = 0; j < 2; j++) {
    const int k = t + 1024 * j;
    pts[k] = make_float4(xb[3 * k + 0], xb[3 * k + 1], xb[3 * k + 2], 0.f);
  }
  __syncthreads();
  const float r2 = (float)(0.3 * 0.3);
  const int w = t >> 6, lane = t & 63;
  const int p = pg + w;
  const float nx = new_xyz[(b * P_ + p) * 3 + 0];
  const float ny = new_xyz[(b * P_ + p) * 3 + 1];
  const float nz = new_xyz[(b * P_ + p) * 3 + 2];
  int* ob = idxw + (b * P_ + p) * S_;
  unsigned msk = 0u;
#pragma unroll
  for (int j = 0; j < 32; j++) {
    const float4 q = pts[j * 64 + lane];
    const float d2 = sqdist_rn(q.x, q.y, q.z, nx, ny, nz);
    msk |= (d2 < r2 ? 1u : 0u) << j;
  }
  int cnt = 0, first = -1;
  for (int j = 0; j < 32; j++) {
    const unsigned long long bal = __ballot((msk >> j) & 1u);
    if (bal != 0ull && first < 0) first = j * 64 + (__ffsll(bal) - 1);
    const int c = (int)__popcll(bal);
    if ((msk >> j) & 1u) {
      const int pos = cnt + (int)__popcll(bal & ((1ull << lane) - 1ull));
      if (pos < S_) ob[pos] = j * 64 + lane;
    }
    cnt += c;
    if (cnt >= S_) break;
  }
  if (cnt < S_ && lane < S_ - cnt) ob[cnt + lane] = first;
}

// ------------------------------------------------------------- SA MLP ------
// Split-f16 MFMA: D = Wh*Xh + Wh*Xl + Wl*Xh (error ~2^-22). 2 proposals
// (32 samples)/block, 8 waves; wave w owns o-tiles {2w,2w+1}; depth-2
// weight-prefetch ring; coalesced transposed-feature staging.
// ROUND-4 CHANGE: fragment-major X layout X[tile=ks*2+st][lane][8]
// (lane = q*16+m, exactly the MFMA B-frag order). B-reads become canonical
// lane-consecutive ds_read_b128 (round-3 layout was (5m+q)%8-quad aliased ->
// ~8-way conflict on EVERY B read; 15.25M conflict cycles saturated the LDS
// pipe). Features shifted to col 8 (cols 3..7 zero, w1 remapped to match) so
// feature octets align with LDS octets -> staging is aligned half8 stores.
__global__ __launch_bounds__(512, 4) void sa_kernel(
    const float* __restrict__ xyz, const float* __restrict__ features,
    const _Float16* __restrict__ ftH, const _Float16* __restrict__ ftL,
    const int use_ft,
    const _Float16* __restrict__ w1h, const _Float16* __restrict__ w1l,
    const _Float16* __restrict__ w2h, const _Float16* __restrict__ w2l,
    const _Float16* __restrict__ w3h, const _Float16* __restrict__ w3l,
    const float* __restrict__ bns, const float* __restrict__ mu,
    const float* __restrict__ bta, const float* __restrict__ new_xyz,
    const int* __restrict__ idxw, float* __restrict__ y) {
  const int blk = blockIdx.x;  // 4096
  const int b = blk >> 7, p0 = (blk & 127) * 2, t = threadIdx.x;
  // X1: 18 tiles (9 ks x 2 st) of [64 lanes][8 halfs]; X2: 16 tiles
  __shared__ __align__(16) _Float16 X1h[18 * 64 * 8];
  __shared__ __align__(16) _Float16 X1l[18 * 64 * 8];
  __shared__ __align__(16) _Float16 X2h[16 * 64 * 8];
  __shared__ __align__(16) _Float16 X2l[16 * 64 * 8];
  __shared__ __align__(16) float red[2 * 256];
  __shared__ int k_sh[32];

  if (t < 32) k_sh[t] = idxw[(b * P_ + p0) * S_ + t];
  // zero pad: ks=8 tiles (16,17), q2 in {1,2,3} (cols 264..287)
  if (t < 96) {
    const int tile = 16 + (t / 48), rem = t % 48;
    const int row = tile * 64 + 16 + rem;  // q2*16+m for q2=1..3 -> rows 16..63
    const half8 z8 = {};
    *(half8*)&X1h[row * 8] = z8;
    *(half8*)&X1l[row * 8] = z8;
  }
  __syncthreads();
  if (t < 32) {
    const int st = t >> 4, m = t & 15, k = k_sh[t];
    const float* xb = xyz + b * K_ * 3;
    const float* nx = new_xyz + (b * P_ + p0 + st) * 3;
    const int base = (st * 64 + m) * 8;  // tile=st (ks=0), q2=0
#pragma unroll
    for (int c = 0; c < 3; c++) {
      const float v = (xb[3 * k + c] - nx[c]) / 0.3f;
      const _Float16 hi = (_Float16)v;
      X1h[base + c] = hi;
      X1l[base + c] = (_Float16)(v - (float)hi);
    }
#pragma unroll
    for (int j = 3; j < 8; j++) {  // cols 3..7 zero
      X1h[base + j] = (_Float16)0.f;
      X1l[base + j] = (_Float16)0.f;
    }
  }
  if (use_ft) {
    // coalesced: 1024 (sample s, octet ch) chunks; feature f -> col c=8+f
    for (int u = t; u < 1024; u += 512) {
      const int s = u >> 5, ch = u & 31;
      const int c = 8 + ch * 8;
      const int ks = c >> 5, q2 = (c >> 3) & 3;
      const int st = s >> 4, m = s & 15;
      const size_t ro = ((size_t)b * K_ + k_sh[s]) * C_ + ch * 8;
      const int dst = ((ks * 2 + st) * 64 + q2 * 16 + m) * 8;
      *(half8*)&X1h[dst] = *(const half8*)&ftH[ro];
      *(half8*)&X1l[dst] = *(const half8*)&ftL[ro];
    }
  } else {
    // fallback: original (C,K) gather; feature cl -> col c=8+cl
    const int cl = t & 255, hf = t >> 8;
    const float* fb = features + (size_t)b * C_ * K_ + (size_t)cl * K_;
    const int c = 8 + cl;
    const int ks = c >> 5, q2 = (c >> 3) & 3, j = c & 7;
    const int s0 = hf * 16;
#pragma unroll 8
    for (int s = s0; s < s0 + 16; s++) {
      const float v = fb[k_sh[s]];
      const _Float16 hi = (_Float16)v;
      const int dst = ((ks * 2 + (s >> 4)) * 64 + q2 * 16 + (s & 15)) * 8 + j;
      X1h[dst] = hi;
      X1l[dst] = (_Float16)(v - (float)hi);
    }
  }

  const int lane = t & 63, w = t >> 6;  // w in 0..7
  const int m = lane & 15, q = lane >> 4;

  f32x4 acc[2][2];
  half8 rAh[2][2], rAl[2][2];  // [parity][i] depth-2 prefetch ring
#pragma unroll
  for (int i = 0; i < 2; i++) {
    rAh[0][i] = *(const half8*)&w1h[(((2 * w + i) * 9 + 0) * 64 + lane) * 8];
    rAl[0][i] = *(const half8*)&w1l[(((2 * w + i) * 9 + 0) * 64 + lane) * 8];
    rAh[1][i] = *(const half8*)&w1h[(((2 * w + i) * 9 + 1) * 64 + lane) * 8];
    rAl[1][i] = *(const half8*)&w1l[(((2 * w + i) * 9 + 1) * 64 + lane) * 8];
  }
  __syncthreads();

#pragma unroll
  for (int l = 0; l < 3; l++) {
    const _Float16* Xih = (l == 1) ? X2h : X1h;
    const _Float16* Xil = (l == 1) ? X2l : X1l;
    const int nks = (l == 0) ? 9 : 8;
    const int base = (l == 0) ? 0 : (l == 1) ? 9 : 17;  // flat step base
#pragma unroll
    for (int i = 0; i < 2; i++) {
      acc[i][0] = (f32x4){0.f, 0.f, 0.f, 0.f};
      acc[i][1] = (f32x4){0.f, 0.f, 0.f, 0.f};
    }
#pragma unroll
    for (int ks = 0; ks < nks; ks++) {
      const int par = (base + ks) & 1;  // compile-time under full unroll
      half8 Ah[2], Al[2];
#pragma unroll
      for (int i = 0; i < 2; i++) { Ah[i] = rAh[par][i]; Al[i] = rAl[par][i]; }
      {
        // prefetch flat-step + 2 into the parity slot just vacated
        int ln = l, kn = ks + 2;
        if (kn >= nks) { kn -= nks; ln = l + 1; }
        if (ln < 3) {
          const _Float16* Ph = (ln == 0) ? w1h : (ln == 1) ? w2h : w3h;
          const _Float16* Pl = (ln == 0) ? w1l : (ln == 1) ? w2l : w3l;
          const int nk2 = (ln == 0) ? 9 : 8;
#pragma unroll
          for (int i = 0; i < 2; i++) {
            const int off = (((2 * w + i) * nk2 + kn) * 64 + lane) * 8;
            rAh[par][i] = *(const half8*)&Ph[off];
            rAl[par][i] = *(const half8*)&Pl[off];
          }
        }
      }
      // canonical frag reads: tile = ks*2+st, lane-consecutive 16B
      const int tb = (ks * 2) * 512 + lane * 8;
      const half8 Bh0 = *(const half8*)&Xih[tb];
      const half8 Bl0 = *(const half8*)&Xil[tb];
      const half8 Bh1 = *(const half8*)&Xih[tb + 512];
      const half8 Bl1 = *(const half8*)&Xil[tb + 512];
#pragma unroll
      for (int i = 0; i < 2; i++) {
        acc[i][0] = MFMA16(Ah[i], Bh0, acc[i][0], 0, 0, 0);
        acc[i][0] = MFMA16(Ah[i], Bl0, acc[i][0], 0, 0, 0);
        acc[i][0] = MFMA16(Al[i], Bh0, acc[i][0], 0, 0, 0);
        acc[i][1] = MFMA16(Ah[i], Bh1, acc[i][1], 0, 0, 0);
        acc[i][1] = MFMA16(Ah[i], Bl1, acc[i][1], 0, 0, 0);
        acc[i][1] = MFMA16(Al[i], Bh1, acc[i][1], 0, 0, 0);
      }
    }

    if (l < 2) {
      _Float16* Xoh = (l == 0) ? X2h : X1h;
      _Float16* Xol = (l == 0) ? X2l : X1l;
#pragma unroll
      for (int i = 0; i < 2; i++) {
        const int c0 = (2 * w + i) * 16 + q * 4;
        const int ks2 = c0 >> 5, q2 = (c0 >> 3) & 3, j0 = c0 & 7;
        const f32x4 sc4 = *(const f32x4*)&bns[l * 256 + c0];
        const f32x4 m4 = *(const f32x4*)&mu[l * 256 + c0];
        const f32x4 b4 = *(const f32x4*)&bta[l * 256 + c0];
#pragma unroll
        for (int s = 0; s < 2; s++) {
          half4h vh, vl;
#pragma unroll
          for (int r = 0; r < 4; r++) {
            const float v = fmaxf((acc[i][s][r] - m4[r]) * sc4[r] + b4[r], 0.f);
            const _Float16 hi = (_Float16)v;
            vh[r] = hi;
            vl[r] = (_Float16)(v - (float)hi);
          }
          const int dst = ((ks2 * 2 + s) * 64 + q2 * 16 + m) * 8 + j0;
          *(half4h*)&Xoh[dst] = vh;
          *(half4h*)&Xol[dst] = vl;
        }
      }
      __syncthreads();
    } else {
#pragma unroll
      for (int i = 0; i < 2; i++)
#pragma unroll
        for (int s = 0; s < 2; s++)
#pragma unroll
          for (int r = 0; r < 4; r++) {
            float v = acc[i][s][r];
            v = fmaxf(v, __shfl_xor(v, 1));
            v = fmaxf(v, __shfl_xor(v, 2));
            v = fmaxf(v, __shfl_xor(v, 4));
            v = fmaxf(v, __shfl_xor(v, 8));
            acc[i][s][r] = v;
          }
      if (m == 0) {
#pragma unroll
        for (int i = 0; i < 2; i++) {
          const int ob = (2 * w + i) * 16 + q * 4;
          *(f32x4*)&red[ob] = acc[i][0];
          *(f32x4*)&red[256 + ob] = acc[i][1];
        }
      }
      __syncthreads();
      // 512 threads cover the 2x256 outputs in one shot
      const int pl = t >> 8, col = t & 255;
      const float sc2 = bns[512 + col];
      const float mu2 = mu[512 + col], bt2 = bta[512 + col];
      const float raw = red[pl * 256 + col];
      y[(b * P_ + p0 + pl) * 256 + col] = fmaxf((raw - mu2) * sc2 + bt2, 0.f);
    }
  }
}

// ------------------------------------------------- P-layers + all heads ----
// l0/l1: split-f16 MFMA. l2 (obj-producing 119x256): EXACT f32 path.
// ROUND-4: Wt layout [qq][oo] -> l2 weight reads are lane-consecutive
// (was stride-80B across lanes, ~4-way bank conflict per read).
__global__ __launch_bounds__(256, 2) void phead_kernel(
    const float* __restrict__ y, const _Float16* __restrict__ p1h,
    const _Float16* __restrict__ p1l, const _Float16* __restrict__ p2h,
    const _Float16* __restrict__ p2l, const float* __restrict__ pw3,
    const float* __restrict__ pb3, const float* __restrict__ bns,
    const float* __restrict__ pm, const float* __restrict__ pb,
    const float* __restrict__ new_xyz, const float* __restrict__ msa,
    float* __restrict__ out) {
  const int blk = blockIdx.x;  // 512
  const int b = blk >> 4, p0 = (blk & 15) * 16, t = threadIdx.x;
  // hand-packed LDS: Wt (l2 only) aliases X0/H (dead by l2)
  __shared__ __align__(16) char smem[58624];
  _Float16* X0h = (_Float16*)smem;             // 16*264*2 = 8448
  _Float16* X0l = (_Float16*)(smem + 8448);    // 8448
  _Float16* Hh  = (_Float16*)(smem + 16896);   // 8448
  _Float16* Hl  = (_Float16*)(smem + 25344);   // 8448 (ends 33792)
  float*    Wt  = (float*)smem;                // 4*128*4 floats = 8192 (alias)
  float*    Y2  = (float*)(smem + 33792);      // 16*260*4 = 16640
  float*    net_s = (float*)(smem + 50432);    // 16*120*4 = 7680

  {
#pragma unroll 4
    for (int s = 0; s < 16; s++) {
      const float v = y[(size_t)(b * P_ + p0 + s) * C_ + t];
      const _Float16 hi = (_Float16)v;
      X0h[s * 264 + t] = hi;
      X0l[s * 264 + t] = (_Float16)(v - (float)hi);
    }
  }
  const int lane = t & 63, w = t >> 6;
  const int m = lane & 15, q = lane >> 4;

  f32x4 acc[4];
  half8 pAh[4], pAl[4];
#pragma unroll
  for (int i = 0; i < 4; i++) {
    const int off = (((4 * w + i) * 8) * 64 + lane) * 8;
    pAh[i] = *(const half8*)&p1h[off];
    pAl[i] = *(const half8*)&p1l[off];
  }
  __syncthreads();

#pragma unroll
  for (int l = 0; l < 2; l++) {
    const _Float16* Xih = l ? Hh : X0h;
    const _Float16* Xil = l ? Hl : X0l;
#pragma unroll
    for (int i = 0; i < 4; i++) acc[i] = (f32x4){0.f, 0.f, 0.f, 0.f};
    for (int ks = 0; ks < 8; ks++) {
      half8 Ah[4], Al[4];
#pragma unroll
      for (int i = 0; i < 4; i++) { Ah[i] = pAh[i]; Al[i] = pAl[i]; }
      {
        int ln = l, kn = ks + 1;
        if (kn == 8) { ln = l + 1; kn = 0; }
        if (ln < 2) {
          const _Float16* Ph = ln ? p2h : p1h;
          const _Float16* Pl = ln ? p2l : p1l;
#pragma unroll
          for (int i = 0; i < 4; i++) {
            const int off = (((4 * w + i) * 8 + kn) * 64 + lane) * 8;
            pAh[i] = *(const half8*)&Ph[off];
            pAl[i] = *(const half8*)&Pl[off];
          }
        }
      }
      const int xo = ks * 32 + q * 8;
      const half8 Bh = *(const half8*)&Xih[m * 264 + xo];
      const half8 Bl = *(const half8*)&Xil[m * 264 + xo];
#pragma unroll
      for (int i = 0; i < 4; i++) {
        acc[i] = MFMA16(Ah[i], Bh, acc[i], 0, 0, 0);
        acc[i] = MFMA16(Ah[i], Bl, acc[i], 0, 0, 0);
        acc[i] = MFMA16(Al[i], Bh, acc[i], 0, 0, 0);
      }
    }
    // epilogue: BN + ReLU; l0 -> H (f16 split), l1 -> Y2 (f32)
#pragma unroll
    for (int i = 0; i < 4; i++) {
      const int ob = (4 * w + i) * 16 + q * 4;
      const f32x4 sc4 = *(const f32x4*)&bns[768 + l * 256 + ob];
      const f32x4 m4 = *(const f32x4*)&pm[l * 256 + ob];
      const f32x4 b4 = *(const f32x4*)&pb[l * 256 + ob];
      if (l == 0) {
        half4h vh, vl;
#pragma unroll
        for (int r = 0; r < 4; r++) {
          const float v = fmaxf((acc[i][r] - m4[r]) * sc4[r] + b4[r], 0.f);
          const _Float16 hi = (_Float16)v;
          vh[r] = hi;
          vl[r] = (_Float16)(v - (float)hi);
        }
        *(half4h*)&Hh[m * 264 + ob] = vh;
        *(half4h*)&Hl[m * 264 + ob] = vl;
      } else {
        f32x4 r4;
#pragma unroll
        for (int r = 0; r < 4; r++)
          r4[r] = fmaxf((acc[i][r] - m4[r]) * sc4[r] + b4[r], 0.f);
        *(f32x4*)&Y2[m * 260 + ob] = r4;
      }
    }
    __syncthreads();
  }

  // final layer (f32, exact): 119 outputs from Y2; Wt aliases X0/H
  {
    const int o = t & 127, ph = t >> 7;
    float a3[8];
#pragma unroll
    for (int pp = 0; pp < 8; pp++) a3[pp] = 0.f;
    for (int tile = 0; tile < 16; tile++) {
      const int c0 = tile * 16;
      for (int u = t; u < 119 * 4; u += 256) {
        int oo = u >> 2, qq = u & 3;
        *(float4*)&Wt[(qq * 128 + oo) * 4] =
            *(const float4*)(pw3 + oo * 256 + c0 + qq * 4);
      }
      __syncthreads();
      if (o < 119) {
#pragma unroll
        for (int j4 = 0; j4 < 4; j4++) {
          const float4 wv = *(const float4*)&Wt[(j4 * 128 + o) * 4];
#pragma unroll
          for (int pp = 0; pp < 8; pp++) {
            const float4 xv =
                *(const float4*)&Y2[(ph * 8 + pp) * 260 + c0 + j4 * 4];
            a3[pp] = fmaf(wv.x, xv.x, a3[pp]);
            a3[pp] = fmaf(wv.y, xv.y, a3[pp]);
            a3[pp] = fmaf(wv.z, xv.z, a3[pp]);
            a3[pp] = fmaf(wv.w, xv.w, a3[pp]);
          }
        }
      }
      __syncthreads();
    }
    if (o < 119) {
      const float bb = pb3[o];
#pragma unroll
      for (int pp = 0; pp < 8; pp++)
        net_s[(ph * 8 + pp) * 120 + o] = a3[pp] + bb;
    }
  }
  __syncthreads();

  if (t < 16) {
    const int gi = b * P_ + p0 + t;
    const float* nr = &net_s[t * 120];
    const float nx = new_xyz[gi * 3 + 0];
    const float ny = new_xyz[gi * 3 + 1];
    const float nz = new_xyz[gi * 3 + 2];
    const float obj0 = nr[0], obj1 = nr[1];
    out[OFF0 + gi * 2 + 0] = obj0;
    out[OFF0 + gi * 2 + 1] = obj1;
    const float cx = nx + nr[2], cy = ny + nr[3], cz = nz + nr[4];
    out[OFF1 + gi * 3 + 0] = cx;
    out[OFF1 + gi * 3 + 1] = cy;
    out[OFF1 + gi * 3 + 2] = cz;
    float bv = -1e30f;
    int bi = 0;
#pragma unroll
    for (int i = 0; i < 18; i++) {
      float v = nr[29 + i];
      out[OFF2 + gi * 18 + i] = v;
      if (v > bv) { bv = v; bi = i; }
    }
#pragma unroll
    for (int i = 0; i < 18; i++)
#pragma unroll
      for (int j = 0; j < 3; j++)
        out[OFF3 + gi * 54 + i * 3 + j] =
            __fmul_rn(nr[47 + i * 3 + j], msa[i * 3 + j]);
    float ps[3];
#pragma unroll
    for (int j = 0; j < 3; j++) {
      ps[j] = __fadd_rn(__fmul_rn(nr[47 + bi * 3 + j], msa[bi * 3 + j]),
                        msa[bi * 3 + j]);
      out[OFF4 + gi * 3 + j] = ps[j];
    }
    float sm = -1e30f;
#pragma unroll
    for (int i = 0; i < 18; i++) {
      float v = nr[101 + i];
      out[OFF5 + gi * 18 + i] = v;
      out[OFF7 + gi * 19 + i] = v;
      sm = fmaxf(sm, v);
    }
    out[OFF7 + gi * 19 + 18] = (obj0 <= obj1) ? 0.f : 1e10f;
    const float cc0 = cx, cc1 = cz, cc2 = -cy;
    const float sxk[8] = {1, 1, -1, -1, 1, 1, -1, -1};
    const float syk[8] = {1, 1, 1, 1, -1, -1, -1, -1};
    const float szk[8] = {1, -1, -1, 1, 1, -1, -1, 1};
#pragma unroll
    for (int k = 0; k < 8; k++) {
      out[OFF6 + gi * 24 + 3 * k + 0] = cc0 + ps[0] * sxk[k] * 0.5f;
      out[OFF6 + gi * 24 + 3 * k + 1] = cc1 + ps[2] * syk[k] * 0.5f;
      out[OFF6 + gi * 24 + 3 * k + 2] = cc2 + ps[1] * szk[k] * 0.5f;
    }
    {
      const float m2 = fmaxf(obj0, obj1);
      const float e0 = expf(obj0 - m2), e1 = expf(obj1 - m2);
      out[OFF8 + gi] = e1 / (e0 + e1);
    }
    {
      float ev[18], es = 0.f;
#pragma unroll
      for (int i = 0; i < 18; i++) {
        ev[i] = expf(nr[101 + i] - sm);
        es += ev[i];
      }
#pragma unroll
      for (int i = 0; i < 18; i++) out[OFF9 + gi * 18 + i] = ev[i] / es;
    }
  }
}

// ---------------------------------------------------------------------------
extern "C" void kernel_launch(void* const* d_in, const int* in_sizes, int n_in,
                              void* d_out, int out_size, void* d_ws,
                              size_t ws_size, hipStream_t stream) {
  (void)in_sizes; (void)n_in; (void)out_size;
  const float* xyz      = (const float*)d_in[0];
  const float* features = (const float*)d_in[1];
  const float* w1       = (const float*)d_in[2];
  const float* w2       = (const float*)d_in[3];
  const float* w3       = (const float*)d_in[4];
  const float* gma      = (const float*)d_in[5];
  const float* bta      = (const float*)d_in[6];
  const float* mu       = (const float*)d_in[7];
  const float* var      = (const float*)d_in[8];
  const float* pw1      = (const float*)d_in[9];
  const float* pw2      = (const float*)d_in[10];
  const float* pw3      = (const float*)d_in[11];
  const float* pb3      = (const float*)d_in[12];
  const float* pg       = (const float*)d_in[13];
  const float* pb       = (const float*)d_in[14];
  const float* pm       = (const float*)d_in[15];
  const float* pv       = (const float*)d_in[16];
  const float* msa      = (const float*)d_in[17];
  float* out = (float*)d_out;

  char* ws = (char*)d_ws;
  float*     new_xyz = (float*)ws;                   // 98304 B
  int*       idxw    = (int*)(ws + 98304);           // 524288 B
  float*     yb      = (float*)(ws + 622592);        // 8388608 B
  _Float16*  w1h     = (_Float16*)(ws + 9011200);    // 147456 B
  _Float16*  w1l     = (_Float16*)(ws + 9158656);    // 147456 B
  _Float16*  w2h     = (_Float16*)(ws + 9306112);    // 131072 B
  _Float16*  w2l     = (_Float16*)(ws + 9437184);    // 131072 B
  _Float16*  w3h     = (_Float16*)(ws + 9568256);    // 131072 B
  _Float16*  w3l     = (_Float16*)(ws + 9699328);    // 131072 B
  float*     bns     = (float*)(ws + 9830400);       // 5120 B (1280 f)
  _Float16*  p1h     = (_Float16*)(ws + 9835520);    // 131072 B
  _Float16*  p1l     = (_Float16*)(ws + 9966592);    // 131072 B
  _Float16*  p2h     = (_Float16*)(ws + 10097664);   // 131072 B
  _Float16*  p2l     = (_Float16*)(ws + 10228736);   // 131072 B -> 10359808
  _Float16*  ftH     = (_Float16*)(ws + 10359808);   // 33554432 B
  _Float16*  ftL     = (_Float16*)(ws + 43914240);   // 33554432 B -> 77468672

  const int use_ft = (ws_size >= 77468672ull) ? 1 : 0;
  const int npre = use_ft ? (197 + 4096) : 197;

  // blocks 0..31: FPS; 32..196: wsplit x4; 197..4292: feature transpose
  fused_pre_kernel<<<npre, 256, 0, stream>>>(xyz, new_xyz, features, ftH, ftL,
                                             w1, w2, w3, pw1, pw2, gma, var,
                                             pg, pv, w1h, w1l, w2h, w2l, w3h,
                                             w3l, p1h, p1l, p2h, p2l, bns);
  ballq_kernel<<<B_ * 16, 1024, 0, stream>>>(xyz, new_xyz, idxw);
  sa_kernel<<<B_ * 128, 512, 0, stream>>>(xyz, features, ftH, ftL, use_ft,
                                          w1h, w1l, w2h, w2l, w3h, w3l, bns,
                                          mu, bta, new_xyz, idxw, yb);
  phead_kernel<<<B_ * 16, 256, 0, stream>>>(yb, p1h, p1l, p2h, p2l, pw3, pb3,
                                            bns, pm, pb, new_xyz, msa, out);
}

// Round 5
// 432.059 us; speedup vs baseline: 1.7939x; 1.0398x over previous
//
#include <hip/hip_runtime.h>
#include <math.h>

#define B_   32
#define K_   2048
#define C_   256
#define P_   256
#define S_   16
#define OUTC 119

// output offsets (floats)
#define OFF0 0        // obj        (B,P,2)
#define OFF1 16384    // center     (B,P,3)
#define OFF2 40960    // size_scores(B,P,18)
#define OFF3 188416   // size_res   (B,P,18,3)
#define OFF4 630784   // pred_size  (B,P,3)
#define OFF5 655360   // sem        (B,P,18)
#define OFF6 802816   // corners    (B,P,8,3)
#define OFF7 999424   // sem_logits (B,P,19)
#define OFF8 1155072  // obj_prob   (B,P)
#define OFF9 1163264  // sem_prob   (B,P,18)

typedef _Float16 half8  __attribute__((ext_vector_type(8)));
typedef _Float16 half4h __attribute__((ext_vector_type(4)));
typedef float    f32x4  __attribute__((ext_vector_type(4)));
#define MFMA16 __builtin_amdgcn_mfma_f32_16x16x32_f16

// X tile stride in half8 rows: 65 (1040B) so tile base byte % 128 = tile*16
// -> tiles spread across bank columns (conflict mitigation for staging).
#define XT 65

__device__ __forceinline__ float sqdist_rn(float ax, float ay, float az,
                                           float bx, float by, float bz) {
  float dx = __fsub_rn(ax, bx), dy = __fsub_rn(ay, by), dz = __fsub_rn(az, bz);
  return __fadd_rn(__fadd_rn(__fmul_rn(dx, dx), __fmul_rn(dy, dy)),
                   __fmul_rn(dz, dz));
}

__device__ __forceinline__ unsigned umax_(unsigned a, unsigned b) {
  return a > b ? a : b;
}
__device__ __forceinline__ unsigned umin_(unsigned a, unsigned b) {
  return a < b ? a : b;
}
// Wave64 u32 max via DPP (row_shr 1/2/4/8 + row_bcast15/31); result valid in
// lane 63. bound_ctrl=false -> invalid source lanes contribute `old`.
__device__ __forceinline__ unsigned wave_red_umax(unsigned x) {
  x = umax_(x, (unsigned)__builtin_amdgcn_update_dpp(0, (int)x, 0x111, 0xf, 0xf, false));
  x = umax_(x, (unsigned)__builtin_amdgcn_update_dpp(0, (int)x, 0x112, 0xf, 0xf, false));
  x = umax_(x, (unsigned)__builtin_amdgcn_update_dpp(0, (int)x, 0x114, 0xf, 0xf, false));
  x = umax_(x, (unsigned)__builtin_amdgcn_update_dpp(0, (int)x, 0x118, 0xf, 0xf, false));
  x = umax_(x, (unsigned)__builtin_amdgcn_update_dpp(0, (int)x, 0x142, 0xf, 0xf, false));
  x = umax_(x, (unsigned)__builtin_amdgcn_update_dpp(0, (int)x, 0x143, 0xf, 0xf, false));
  return x;
}
__device__ __forceinline__ unsigned wave_red_umin(unsigned x) {
  x = umin_(x, (unsigned)__builtin_amdgcn_update_dpp(-1, (int)x, 0x111, 0xf, 0xf, false));
  x = umin_(x, (unsigned)__builtin_amdgcn_update_dpp(-1, (int)x, 0x112, 0xf, 0xf, false));
  x = umin_(x, (unsigned)__builtin_amdgcn_update_dpp(-1, (int)x, 0x114, 0xf, 0xf, false));
  x = umin_(x, (unsigned)__builtin_amdgcn_update_dpp(-1, (int)x, 0x118, 0xf, 0xf, false));
  x = umin_(x, (unsigned)__builtin_amdgcn_update_dpp(-1, (int)x, 0x142, 0xf, 0xf, false));
  x = umin_(x, (unsigned)__builtin_amdgcn_update_dpp(-1, (int)x, 0x143, 0xf, 0xf, false));
  return x;
}

// ------------------------------------------- weight split to f16 hi/lo -----
// Fragment-order layout: Wf[tile = ot*nks + ks][lane][8] -> A-frag load is
// one coalesced 1KB wave read. w1 columns remapped to octet-aligned X
// layout: c 0..2 = xyz, c 3..7 = zero, c 8..263 = features, c>=264 zero.
__device__ __forceinline__ void wsplit_body(
    int r, int t, const float* __restrict__ w1, const float* __restrict__ w2,
    const float* __restrict__ w3, const float* __restrict__ pw1,
    const float* __restrict__ pw2, const float* __restrict__ gma,
    const float* __restrict__ var, const float* __restrict__ pg,
    const float* __restrict__ pv, _Float16* __restrict__ w1h,
    _Float16* __restrict__ w1l, _Float16* __restrict__ w2h,
    _Float16* __restrict__ w2l, _Float16* __restrict__ w3h,
    _Float16* __restrict__ w3l, _Float16* __restrict__ p1h,
    _Float16* __restrict__ p1l, _Float16* __restrict__ p2h,
    _Float16* __restrict__ p2l, float* __restrict__ bns) {
  if (r == 656) {
    for (int u = t; u < 768; u += 64) bns[u] = gma[u] / sqrtf(var[u] + 1e-5f);
    for (int u = t; u < 512; u += 64)
      bns[768 + u] = pg[u] / sqrtf(pv[u] + 1e-5f);
    return;
  }
  const float* src;
  _Float16 *dh, *dl;
  int ot, ks, nks, K, remap = 0;
  if (r < 144) {
    src = w1; dh = w1h; dl = w1l; ot = r / 9; ks = r % 9; nks = 9; K = 259;
    remap = 1;
  } else if (r < 272) {
    const int rr = r - 144;
    src = w2; dh = w2h; dl = w2l; ot = rr >> 3; ks = rr & 7; nks = 8; K = 256;
  } else if (r < 400) {
    const int rr = r - 272;
    src = w3; dh = w3h; dl = w3l; ot = rr >> 3; ks = rr & 7; nks = 8; K = 256;
  } else if (r < 528) {
    const int rr = r - 400;
    src = pw1; dh = p1h; dl = p1l; ot = rr >> 3; ks = rr & 7; nks = 8; K = 256;
  } else {
    const int rr = r - 528;
    src = pw2; dh = p2h; dl = p2l; ot = rr >> 3; ks = rr & 7; nks = 8; K = 256;
  }
  const int m = t & 15, q = t >> 4;
  const float* row = src + (ot * 16 + m) * K;
  half8 vh, vl;
#pragma unroll
  for (int j = 0; j < 8; j++) {
    const int c = ks * 32 + q * 8 + j;
    float v;
    if (remap) {
      v = (c < 3) ? row[c] : (c >= 8 && c < 264) ? row[c - 5] : 0.f;
    } else {
      v = (c < K) ? row[c] : 0.f;
    }
    const _Float16 hi = (_Float16)v;
    vh[j] = hi;
    vl[j] = (_Float16)(v - (float)hi);
  }
  const int base = ((ot * nks + ks) * 64 + t) * 8;
  *(half8*)&dh[base] = vh;
  *(half8*)&dl[base] = vl;
}

// ---------------------- fused FPS (4-wave) + wsplit + feature transpose ----
__global__ __launch_bounds__(256) void fused_pre_kernel(
    const float* __restrict__ xyz, float* __restrict__ new_xyz,
    const float* __restrict__ features, _Float16* __restrict__ ftH,
    _Float16* __restrict__ ftL,
    const float* __restrict__ w1, const float* __restrict__ w2,
    const float* __restrict__ w3, const float* __restrict__ pw1,
    const float* __restrict__ pw2, const float* __restrict__ gma,
    const float* __restrict__ var, const float* __restrict__ pg,
    const float* __restrict__ pv, _Float16* __restrict__ w1h,
    _Float16* __restrict__ w1l, _Float16* __restrict__ w2h,
    _Float16* __restrict__ w2l, _Float16* __restrict__ w3h,
    _Float16* __restrict__ w3l, _Float16* __restrict__ p1h,
    _Float16* __restrict__ p1l, _Float16* __restrict__ p2h,
    _Float16* __restrict__ p2l, float* __restrict__ bns) {
  __shared__ __align__(16) char smem_pre[32768];  // pts (fps) | tl (transpose)
  __shared__ uint2 redw[2][4];
  const int bid = blockIdx.x;

  if (bid >= 197) {
    // ---- feature transpose tile: 64 c x 64 k ----
    const int idx = bid - 197;                 // [0, 4096)
    const int b = idx >> 7, rem = idx & 127;
    const int c0 = (rem >> 5) * 64, k0 = (rem & 31) * 64;
    float* tl = (float*)smem_pre;              // [64][65]
    const int w = threadIdx.x >> 6, lane = threadIdx.x & 63;
    const float* fb = features + (size_t)b * C_ * K_;
#pragma unroll
    for (int r = 0; r < 16; r++) {
      const int cl = r * 4 + w;
      tl[cl * 65 + lane] = fb[(size_t)(c0 + cl) * K_ + k0 + lane];
    }
    __syncthreads();
#pragma unroll
    for (int r = 0; r < 16; r++) {
      const int kl = r * 4 + w;
      const float v = tl[lane * 65 + kl];
      const _Float16 hi = (_Float16)v;
      const size_t o = ((size_t)b * K_ + k0 + kl) * C_ + c0 + lane;
      ftH[o] = hi;
      ftL[o] = (_Float16)(v - (float)hi);
    }
    return;
  }

  if (bid >= 32) {
    const int sub = (bid - 32) * 4 + (threadIdx.x >> 6);
    if (sub < 657)
      wsplit_body(sub, threadIdx.x & 63, w1, w2, w3, pw1, pw2, gma, var, pg,
                  pv, w1h, w1l, w2h, w2l, w3h, w3l, p1h, p1l, p2h, p2l, bns);
    return;
  }

  // ---- FPS ----
  const int b = bid, t = threadIdx.x;
  const int lane = t & 63, w = t >> 6;
  float4* pts = (float4*)smem_pre;  // [K_]
  const float* xb = xyz + b * K_ * 3;
  float px[8], py[8], pz[8], dist[8];
#pragma unroll
  for (int j = 0; j < 8; j++) {
    const int k = t + 256 * j;
    const float x = xb[3 * k + 0];
    const float yv = xb[3 * k + 1];
    const float z = xb[3 * k + 2];
    px[j] = x; py[j] = yv; pz[j] = z;
    dist[j] = 1e10f;
    pts[k] = make_float4(x, yv, z, 0.f);
  }
  __syncthreads();
  int far = 0;
  for (int i = 0; i < P_; i++) {
    const float4 c = pts[far];  // uniform address -> LDS broadcast
    if (t == 0) {
      float* nx = new_xyz + (b * P_ + i) * 3;
      nx[0] = c.x; nx[1] = c.y; nx[2] = c.z;
    }
    float bv = -1.f;
    int bj = 0;
#pragma unroll
    for (int j = 0; j < 8; j++) {
      const float d = sqdist_rn(px[j], py[j], pz[j], c.x, c.y, c.z);
      dist[j] = fminf(dist[j], d);
      if (dist[j] > bv) { bv = dist[j]; bj = j; }  // strict > keeps lowest j
    }
    const unsigned bvb = __float_as_uint(bv);
    const unsigned gw = wave_red_umax(bvb);
    const unsigned gmaxw = (unsigned)__builtin_amdgcn_readlane((int)gw, 63);
    const unsigned kg = (unsigned)(bj * 256 + t);  // == global point index k
    const unsigned key2 = (bvb == gmaxw) ? kg : 0xFFFFFFFFu;
    const unsigned kw = wave_red_umin(key2);
    if (lane == 63) redw[i & 1][w] = make_uint2(gmaxw, kw);
    __syncthreads();
    const uint2 r0 = redw[i & 1][0], r1 = redw[i & 1][1];
    const uint2 r2 = redw[i & 1][2], r3 = redw[i & 1][3];
    const unsigned g = umax_(umax_(r0.x, r1.x), umax_(r2.x, r3.x));
    unsigned fk = 0xFFFFFFFFu;
    if (r0.x == g) fk = umin_(fk, r0.y);
    if (r1.x == g) fk = umin_(fk, r1.y);
    if (r2.x == g) fk = umin_(fk, r2.y);
    if (r3.x == g) fk = umin_(fk, r3.y);
    far = (int)fk;
  }
}

// ---------------------------------------------------------- ball query -----
// One WAVE per proposal; 32-bit hit mask per lane, ballot+popcount prefix
// emits the first 16 hits in exact ascending-k order.
__global__ __launch_bounds__(1024) void ballq_kernel(
    const float* __restrict__ xyz, const float* __restrict__ new_xyz,
    int* __restrict__ idxw) {
  const int blk = blockIdx.x;  // 512 = 32 batches x 16 groups
  const int b = blk >> 4, pg = (blk & 15) * 16, t = threadIdx.x;
  __shared__ __align__(16) float4 pts[K_];  // 32 KB
  const float* xb = xyz + b * K_ * 3;
#pragma unroll
  for (int j = 0; j < 2; j++) {
    const int k = t + 1024 * j;
    pts[k] = make_float4(xb[3 * k + 0], xb[3 * k + 1], xb[3 * k + 2], 0.f);
  }
  __syncthreads();
  const float r2 = (float)(0.3 * 0.3);
  const int w = t >> 6, lane = t & 63;
  const int p = pg + w;
  const float nx = new_xyz[(b * P_ + p) * 3 + 0];
  const float ny = new_xyz[(b * P_ + p) * 3 + 1];
  const float nz = new_xyz[(b * P_ + p) * 3 + 2];
  int* ob = idxw + (b * P_ + p) * S_;
  unsigned msk = 0u;
#pragma unroll
  for (int j = 0; j < 32; j++) {
    const float4 q = pts[j * 64 + lane];
    const float d2 = sqdist_rn(q.x, q.y, q.z, nx, ny, nz);
    msk |= (d2 < r2 ? 1u : 0u) << j;
  }
  int cnt = 0, first = -1;
  for (int j = 0; j < 32; j++) {
    const unsigned long long bal = __ballot((msk >> j) & 1u);
    if (bal != 0ull && first < 0) first = j * 64 + (__ffsll(bal) - 1);
    const int c = (int)__popcll(bal);
    if ((msk >> j) & 1u) {
      const int pos = cnt + (int)__popcll(bal & ((1ull << lane) - 1ull));
      if (pos < S_) ob[pos] = j * 64 + lane;
    }
    cnt += c;
    if (cnt >= S_) break;
  }
  if (cnt < S_ && lane < S_ - cnt) ob[cnt + lane] = first;
}

// ------------------------------------------------------------- SA MLP ------
// Split-f16 MFMA: D = Wh*Xh + Wh*Xl + Wl*Xh. ROUND-5 CHANGES:
// (1) 4 proposals (64 samples)/block -> weight L2 traffic halved (3.36GB ->
//     1.68GB) and 24 MFMA per k-step per wave (2 o-tiles x 4 s-tiles) for
//     the same per-step load latencies (better ILP).
// (2) IN-PLACE X: one buffer for all 3 layers. Legal because a barrier
//     after each k-loop makes input tiles dead before epilogue overwrites.
// (3) XOR row swizzle (row ^= ks&7) + tile stride 65 half8s (1040B): B-reads
//     stay a bijection onto a contiguous 1KB span (conflict-free); staging
//     writes spread from 32-way (tile/q2 strides = 0 mod 128 !) to ~4-way.
// LDS 79.2KB -> 2 blocks/CU, 16 waves/CU.
__global__ __launch_bounds__(512, 4) void sa_kernel(
    const float* __restrict__ xyz, const float* __restrict__ features,
    const _Float16* __restrict__ ftH, const _Float16* __restrict__ ftL,
    const int use_ft,
    const _Float16* __restrict__ w1h, const _Float16* __restrict__ w1l,
    const _Float16* __restrict__ w2h, const _Float16* __restrict__ w2l,
    const _Float16* __restrict__ w3h, const _Float16* __restrict__ w3l,
    const float* __restrict__ bns, const float* __restrict__ mu,
    const float* __restrict__ bta, const float* __restrict__ new_xyz,
    const int* __restrict__ idxw, float* __restrict__ y) {
  const int blk = blockIdx.x;  // 2048
  const int b = blk >> 6, p0 = (blk & 63) * 4, t = threadIdx.x;
  // 36 tiles (9 ks x 4 st) of [65 rows][8 halfs]; in-place across layers
  __shared__ __align__(16) _Float16 Xh[36 * XT * 8];
  __shared__ __align__(16) _Float16 Xl[36 * XT * 8];
  __shared__ __align__(16) float red[4 * 256];
  __shared__ int k_sh[64];

  if (t < 64) k_sh[t] = idxw[(b * P_ + p0) * S_ + t];
  // zero pad: ks=8 tiles (32..35), rows 16..63 (cols 264..287); swizzle c=0
  if (t < 192) {
    const int tile = 32 + t / 48, row = 16 + (t % 48);
    const half8 z8 = {};
    *(half8*)&Xh[(tile * XT + row) * 8] = z8;
    *(half8*)&Xl[(tile * XT + row) * 8] = z8;
  }
  __syncthreads();
  if (t < 64) {
    const int st = t >> 4, m = t & 15, k = k_sh[t];
    const float* xb = xyz + b * K_ * 3;
    const float* nx = new_xyz + (b * P_ + p0 + st) * 3;
    const int base = (st * XT + m) * 8;  // tile=st (ks=0), q2=0, swizzle c=0
#pragma unroll
    for (int c = 0; c < 3; c++) {
      const float v = (xb[3 * k + c] - nx[c]) / 0.3f;
      const _Float16 hi = (_Float16)v;
      Xh[base + c] = hi;
      Xl[base + c] = (_Float16)(v - (float)hi);
    }
#pragma unroll
    for (int j = 3; j < 8; j++) {  // cols 3..7 zero
      Xh[base + j] = (_Float16)0.f;
      Xl[base + j] = (_Float16)0.f;
    }
  }
  if (use_ft) {
    // coalesced: 2048 (sample s, octet ch) chunks; feature f -> col c=8+f
    for (int u = t; u < 2048; u += 512) {
      const int s = u >> 5, ch = u & 31;
      const int c = 8 + ch * 8;
      const int ks = c >> 5, q2 = (c >> 3) & 3;
      const int st = s >> 4, m = s & 15;
      const size_t ro = ((size_t)b * K_ + k_sh[s]) * C_ + ch * 8;
      const int row = (q2 * 16 + m) ^ (ks & 7);
      const int dst = ((ks * 4 + st) * XT + row) * 8;
      *(half8*)&Xh[dst] = *(const half8*)&ftH[ro];
      *(half8*)&Xl[dst] = *(const half8*)&ftL[ro];
    }
  } else {
    // fallback: original (C,K) gather; feature cl -> col c=8+cl
    const int cl = t & 255, hf = t >> 8;
    const float* fb = features + (size_t)b * C_ * K_ + (size_t)cl * K_;
    const int c = 8 + cl;
    const int ks = c >> 5, q2 = (c >> 3) & 3, j = c & 7;
    const int s0 = hf * 32;
#pragma unroll 8
    for (int s = s0; s < s0 + 32; s++) {
      const float v = fb[k_sh[s]];
      const _Float16 hi = (_Float16)v;
      const int row = (q2 * 16 + (s & 15)) ^ (ks & 7);
      const int dst = ((ks * 4 + (s >> 4)) * XT + row) * 8 + j;
      Xh[dst] = hi;
      Xl[dst] = (_Float16)(v - (float)hi);
    }
  }

  const int lane = t & 63, w = t >> 6;  // w in 0..7
  const int m = lane & 15, q = lane >> 4;

  f32x4 acc[2][4];
  half8 rAh[2][2], rAl[2][2];  // [parity][i] depth-2 prefetch ring
#pragma unroll
  for (int i = 0; i < 2; i++) {
    rAh[0][i] = *(const half8*)&w1h[(((2 * w + i) * 9 + 0) * 64 + lane) * 8];
    rAl[0][i] = *(const half8*)&w1l[(((2 * w + i) * 9 + 0) * 64 + lane) * 8];
    rAh[1][i] = *(const half8*)&w1h[(((2 * w + i) * 9 + 1) * 64 + lane) * 8];
    rAl[1][i] = *(const half8*)&w1l[(((2 * w + i) * 9 + 1) * 64 + lane) * 8];
  }
  __syncthreads();

#pragma unroll
  for (int l = 0; l < 3; l++) {
    const int nks = (l == 0) ? 9 : 8;
    const int base = (l == 0) ? 0 : (l == 1) ? 9 : 17;  // flat step base
#pragma unroll
    for (int i = 0; i < 2; i++)
#pragma unroll
      for (int s = 0; s < 4; s++) acc[i][s] = (f32x4){0.f, 0.f, 0.f, 0.f};
#pragma unroll
    for (int ks = 0; ks < nks; ks++) {
      const int par = (base + ks) & 1;  // compile-time under full unroll
      half8 Ah[2], Al[2];
#pragma unroll
      for (int i = 0; i < 2; i++) { Ah[i] = rAh[par][i]; Al[i] = rAl[par][i]; }
      {
        // prefetch flat-step + 2 into the parity slot just vacated
        int ln = l, kn = ks + 2;
        if (kn >= nks) { kn -= nks; ln = l + 1; }
        if (ln < 3) {
          const _Float16* Ph = (ln == 0) ? w1h : (ln == 1) ? w2h : w3h;
          const _Float16* Pl = (ln == 0) ? w1l : (ln == 1) ? w2l : w3l;
          const int nk2 = (ln == 0) ? 9 : 8;
#pragma unroll
          for (int i = 0; i < 2; i++) {
            const int off = (((2 * w + i) * nk2 + kn) * 64 + lane) * 8;
            rAh[par][i] = *(const half8*)&Ph[off];
            rAl[par][i] = *(const half8*)&Pl[off];
          }
        }
      }
      // B-frag reads: tile = ks*4+s, row = lane ^ (ks&7) (bijective 1KB span)
      const int rsw = lane ^ (ks & 7);
#pragma unroll
      for (int s = 0; s < 4; s++) {
        const int tb = ((ks * 4 + s) * XT + rsw) * 8;
        const half8 Bh = *(const half8*)&Xh[tb];
        const half8 Bl = *(const half8*)&Xl[tb];
#pragma unroll
        for (int i = 0; i < 2; i++) {
          acc[i][s] = MFMA16(Ah[i], Bh, acc[i][s], 0, 0, 0);
          acc[i][s] = MFMA16(Ah[i], Bl, acc[i][s], 0, 0, 0);
          acc[i][s] = MFMA16(Al[i], Bh, acc[i][s], 0, 0, 0);
        }
      }
    }

    if (l < 2) {
      __syncthreads();  // in-place: all waves done READING X before overwrite
#pragma unroll
      for (int i = 0; i < 2; i++) {
        const int c0 = (2 * w + i) * 16 + q * 4;
        const int ks2 = c0 >> 5, q2 = (c0 >> 3) & 3, j0 = c0 & 7;
        const f32x4 sc4 = *(const f32x4*)&bns[l * 256 + c0];
        const f32x4 m4 = *(const f32x4*)&mu[l * 256 + c0];
        const f32x4 b4 = *(const f32x4*)&bta[l * 256 + c0];
        const int row = (q2 * 16 + m) ^ (ks2 & 7);
#pragma unroll
        for (int s = 0; s < 4; s++) {
          half4h vh, vl;
#pragma unroll
          for (int r = 0; r < 4; r++) {
            const float v = fmaxf((acc[i][s][r] - m4[r]) * sc4[r] + b4[r], 0.f);
            const _Float16 hi = (_Float16)v;
            vh[r] = hi;
            vl[r] = (_Float16)(v - (float)hi);
          }
          const int dst = ((ks2 * 4 + s) * XT + row) * 8 + j0;
          *(half4h*)&Xh[dst] = vh;
          *(half4h*)&Xl[dst] = vl;
        }
      }
      __syncthreads();
    } else {
#pragma unroll
      for (int i = 0; i < 2; i++)
#pragma unroll
        for (int s = 0; s < 4; s++)
#pragma unroll
          for (int r = 0; r < 4; r++) {
            float v = acc[i][s][r];
            v = fmaxf(v, __shfl_xor(v, 1));
            v = fmaxf(v, __shfl_xor(v, 2));
            v = fmaxf(v, __shfl_xor(v, 4));
            v = fmaxf(v, __shfl_xor(v, 8));
            acc[i][s][r] = v;
          }
      if (m == 0) {
#pragma unroll
        for (int i = 0; i < 2; i++) {
          const int ob = (2 * w + i) * 16 + q * 4;
#pragma unroll
          for (int s = 0; s < 4; s++) *(f32x4*)&red[s * 256 + ob] = acc[i][s];
        }
      }
      __syncthreads();
      // 512 threads cover the 4x256 outputs in two passes
      for (int u = t; u < 1024; u += 512) {
        const int pl = u >> 8, col = u & 255;
        const float sc2 = bns[512 + col];
        const float mu2 = mu[512 + col], bt2 = bta[512 + col];
        const float raw = red[pl * 256 + col];
        y[(b * P_ + p0 + pl) * 256 + col] = fmaxf((raw - mu2) * sc2 + bt2, 0.f);
      }
    }
  }
}

// ------------------------------------------------- P-layers + all heads ----
// l0/l1: split-f16 MFMA. l2 (obj-producing 119x256): EXACT f32 path.
// Wt layout [qq][oo] -> l2 weight reads lane-consecutive (conflict-free).
__global__ __launch_bounds__(256, 2) void phead_kernel(
    const float* __restrict__ y, const _Float16* __restrict__ p1h,
    const _Float16* __restrict__ p1l, const _Float16* __restrict__ p2h,
    const _Float16* __restrict__ p2l, const float* __restrict__ pw3,
    const float* __restrict__ pb3, const float* __restrict__ bns,
    const float* __restrict__ pm, const float* __restrict__ pb,
    const float* __restrict__ new_xyz, const float* __restrict__ msa,
    float* __restrict__ out) {
  const int blk = blockIdx.x;  // 512
  const int b = blk >> 4, p0 = (blk & 15) * 16, t = threadIdx.x;
  // hand-packed LDS: Wt (l2 only) aliases X0/H (dead by l2)
  __shared__ __align__(16) char smem[58624];
  _Float16* X0h = (_Float16*)smem;             // 16*264*2 = 8448
  _Float16* X0l = (_Float16*)(smem + 8448);    // 8448
  _Float16* Hh  = (_Float16*)(smem + 16896);   // 8448
  _Float16* Hl  = (_Float16*)(smem + 25344);   // 8448 (ends 33792)
  float*    Wt  = (float*)smem;                // 4*128*4 floats = 8192 (alias)
  float*    Y2  = (float*)(smem + 33792);      // 16*260*4 = 16640
  float*    net_s = (float*)(smem + 50432);    // 16*120*4 = 7680

  {
#pragma unroll 4
    for (int s = 0; s < 16; s++) {
      const float v = y[(size_t)(b * P_ + p0 + s) * C_ + t];
      const _Float16 hi = (_Float16)v;
      X0h[s * 264 + t] = hi;
      X0l[s * 264 + t] = (_Float16)(v - (float)hi);
    }
  }
  const int lane = t & 63, w = t >> 6;
  const int m = lane & 15, q = lane >> 4;

  f32x4 acc[4];
  half8 pAh[4], pAl[4];
#pragma unroll
  for (int i = 0; i < 4; i++) {
    const int off = (((4 * w + i) * 8) * 64 + lane) * 8;
    pAh[i] = *(const half8*)&p1h[off];
    pAl[i] = *(const half8*)&p1l[off];
  }
  __syncthreads();

#pragma unroll
  for (int l = 0; l < 2; l++) {
    const _Float16* Xih = l ? Hh : X0h;
    const _Float16* Xil = l ? Hl : X0l;
#pragma unroll
    for (int i = 0; i < 4; i++) acc[i] = (f32x4){0.f, 0.f, 0.f, 0.f};
    for (int ks = 0; ks < 8; ks++) {
      half8 Ah[4], Al[4];
#pragma unroll
      for (int i = 0; i < 4; i++) { Ah[i] = pAh[i]; Al[i] = pAl[i]; }
      {
        int ln = l, kn = ks + 1;
        if (kn == 8) { ln = l + 1; kn = 0; }
        if (ln < 2) {
          const _Float16* Ph = ln ? p2h : p1h;
          const _Float16* Pl = ln ? p2l : p1l;
#pragma unroll
          for (int i = 0; i < 4; i++) {
            const int off = (((4 * w + i) * 8 + kn) * 64 + lane) * 8;
            pAh[i] = *(const half8*)&Ph[off];
            pAl[i] = *(const half8*)&Pl[off];
          }
        }
      }
      const int xo = ks * 32 + q * 8;
      const half8 Bh = *(const half8*)&Xih[m * 264 + xo];
      const half8 Bl = *(const half8*)&Xil[m * 264 + xo];
#pragma unroll
      for (int i = 0; i < 4; i++) {
        acc[i] = MFMA16(Ah[i], Bh, acc[i], 0, 0, 0);
        acc[i] = MFMA16(Ah[i], Bl, acc[i], 0, 0, 0);
        acc[i] = MFMA16(Al[i], Bh, acc[i], 0, 0, 0);
      }
    }
    // epilogue: BN + ReLU; l0 -> H (f16 split), l1 -> Y2 (f32)
#pragma unroll
    for (int i = 0; i < 4; i++) {
      const int ob = (4 * w + i) * 16 + q * 4;
      const f32x4 sc4 = *(const f32x4*)&bns[768 + l * 256 + ob];
      const f32x4 m4 = *(const f32x4*)&pm[l * 256 + ob];
      const f32x4 b4 = *(const f32x4*)&pb[l * 256 + ob];
      if (l == 0) {
        half4h vh, vl;
#pragma unroll
        for (int r = 0; r < 4; r++) {
          const float v = fmaxf((acc[i][r] - m4[r]) * sc4[r] + b4[r], 0.f);
          const _Float16 hi = (_Float16)v;
          vh[r] = hi;
          vl[r] = (_Float16)(v - (float)hi);
        }
        *(half4h*)&Hh[m * 264 + ob] = vh;
        *(half4h*)&Hl[m * 264 + ob] = vl;
      } else {
        f32x4 r4;
#pragma unroll
        for (int r = 0; r < 4; r++)
          r4[r] = fmaxf((acc[i][r] - m4[r]) * sc4[r] + b4[r], 0.f);
        *(f32x4*)&Y2[m * 260 + ob] = r4;
      }
    }
    __syncthreads();
  }

  // final layer (f32, exact): 119 outputs from Y2; Wt aliases X0/H
  {
    const int o = t & 127, ph = t >> 7;
    float a3[8];
#pragma unroll
    for (int pp = 0; pp < 8; pp++) a3[pp] = 0.f;
    for (int tile = 0; tile < 16; tile++) {
      const int c0 = tile * 16;
      for (int u = t; u < 119 * 4; u += 256) {
        int oo = u >> 2, qq = u & 3;
        *(float4*)&Wt[(qq * 128 + oo) * 4] =
            *(const float4*)(pw3 + oo * 256 + c0 + qq * 4);
      }
      __syncthreads();
      if (o < 119) {
#pragma unroll
        for (int j4 = 0; j4 < 4; j4++) {
          const float4 wv = *(const float4*)&Wt[(j4 * 128 + o) * 4];
#pragma unroll
          for (int pp = 0; pp < 8; pp++) {
            const float4 xv =
                *(const float4*)&Y2[(ph * 8 + pp) * 260 + c0 + j4 * 4];
            a3[pp] = fmaf(wv.x, xv.x, a3[pp]);
            a3[pp] = fmaf(wv.y, xv.y, a3[pp]);
            a3[pp] = fmaf(wv.z, xv.z, a3[pp]);
            a3[pp] = fmaf(wv.w, xv.w, a3[pp]);
          }
        }
      }
      __syncthreads();
    }
    if (o < 119) {
      const float bb = pb3[o];
#pragma unroll
      for (int pp = 0; pp < 8; pp++)
        net_s[(ph * 8 + pp) * 120 + o] = a3[pp] + bb;
    }
  }
  __syncthreads();

  if (t < 16) {
    const int gi = b * P_ + p0 + t;
    const float* nr = &net_s[t * 120];
    const float nx = new_xyz[gi * 3 + 0];
    const float ny = new_xyz[gi * 3 + 1];
    const float nz = new_xyz[gi * 3 + 2];
    const float obj0 = nr[0], obj1 = nr[1];
    out[OFF0 + gi * 2 + 0] = obj0;
    out[OFF0 + gi * 2 + 1] = obj1;
    const float cx = nx + nr[2], cy = ny + nr[3], cz = nz + nr[4];
    out[OFF1 + gi * 3 + 0] = cx;
    out[OFF1 + gi * 3 + 1] = cy;
    out[OFF1 + gi * 3 + 2] = cz;
    float bv = -1e30f;
    int bi = 0;
#pragma unroll
    for (int i = 0; i < 18; i++) {
      float v = nr[29 + i];
      out[OFF2 + gi * 18 + i] = v;
      if (v > bv) { bv = v; bi = i; }
    }
#pragma unroll
    for (int i = 0; i < 18; i++)
#pragma unroll
      for (int j = 0; j < 3; j++)
        out[OFF3 + gi * 54 + i * 3 + j] =
            __fmul_rn(nr[47 + i * 3 + j], msa[i * 3 + j]);
    float ps[3];
#pragma unroll
    for (int j = 0; j < 3; j++) {
      ps[j] = __fadd_rn(__fmul_rn(nr[47 + bi * 3 + j], msa[bi * 3 + j]),
                        msa[bi * 3 + j]);
      out[OFF4 + gi * 3 + j] = ps[j];
    }
    float sm = -1e30f;
#pragma unroll
    for (int i = 0; i < 18; i++) {
      float v = nr[101 + i];
      out[OFF5 + gi * 18 + i] = v;
      out[OFF7 + gi * 19 + i] = v;
      sm = fmaxf(sm, v);
    }
    out[OFF7 + gi * 19 + 18] = (obj0 <= obj1) ? 0.f : 1e10f;
    const float cc0 = cx, cc1 = cz, cc2 = -cy;
    const float sxk[8] = {1, 1, -1, -1, 1, 1, -1, -1};
    const float syk[8] = {1, 1, 1, 1, -1, -1, -1, -1};
    const float szk[8] = {1, -1, -1, 1, 1, -1, -1, 1};
#pragma unroll
    for (int k = 0; k < 8; k++) {
      out[OFF6 + gi * 24 + 3 * k + 0] = cc0 + ps[0] * sxk[k] * 0.5f;
      out[OFF6 + gi * 24 + 3 * k + 1] = cc1 + ps[2] * syk[k] * 0.5f;
      out[OFF6 + gi * 24 + 3 * k + 2] = cc2 + ps[1] * szk[k] * 0.5f;
    }
    {
      const float m2 = fmaxf(obj0, obj1);
      const float e0 = expf(obj0 - m2), e1 = expf(obj1 - m2);
      out[OFF8 + gi] = e1 / (e0 + e1);
    }
    {
      float ev[18], es = 0.f;
#pragma unroll
      for (int i = 0; i < 18; i++) {
        ev[i] = expf(nr[101 + i] - sm);
        es += ev[i];
      }
#pragma unroll
      for (int i = 0; i < 18; i++) out[OFF9 + gi * 18 + i] = ev[i] / es;
    }
  }
}

// ---------------------------------------------------------------------------
extern "C" void kernel_launch(void* const* d_in, const int* in_sizes, int n_in,
                              void* d_out, int out_size, void* d_ws,
                              size_t ws_size, hipStream_t stream) {
  (void)in_sizes; (void)n_in; (void)out_size;
  const float* xyz      = (const float*)d_in[0];
  const float* features = (const float*)d_in[1];
  const float* w1       = (const float*)d_in[2];
  const float* w2       = (const float*)d_in[3];
  const float* w3       = (const float*)d_in[4];
  const float* gma      = (const float*)d_in[5];
  const float* bta      = (const float*)d_in[6];
  const float* mu       = (const float*)d_in[7];
  const float* var      = (const float*)d_in[8];
  const float* pw1      = (const float*)d_in[9];
  const float* pw2      = (const float*)d_in[10];
  const float* pw3      = (const float*)d_in[11];
  const float* pb3      = (const float*)d_in[12];
  const float* pg       = (const float*)d_in[13];
  const float* pb       = (const float*)d_in[14];
  const float* pm       = (const float*)d_in[15];
  const float* pv       = (const float*)d_in[16];
  const float* msa      = (const float*)d_in[17];
  float* out = (float*)d_out;

  char* ws = (char*)d_ws;
  float*     new_xyz = (float*)ws;                   // 98304 B
  int*       idxw    = (int*)(ws + 98304);           // 524288 B
  float*     yb      = (float*)(ws + 622592);        // 8388608 B
  _Float16*  w1h     = (_Float16*)(ws + 9011200);    // 147456 B
  _Float16*  w1l     = (_Float16*)(ws + 9158656);    // 147456 B
  _Float16*  w2h     = (_Float16*)(ws + 9306112);    // 131072 B
  _Float16*  w2l     = (_Float16*)(ws + 9437184);    // 131072 B
  _Float16*  w3h     = (_Float16*)(ws + 9568256);    // 131072 B
  _Float16*  w3l     = (_Float16*)(ws + 9699328);    // 131072 B
  float*     bns     = (float*)(ws + 9830400);       // 5120 B (1280 f)
  _Float16*  p1h     = (_Float16*)(ws + 9835520);    // 131072 B
  _Float16*  p1l     = (_Float16*)(ws + 9966592);    // 131072 B
  _Float16*  p2h     = (_Float16*)(ws + 10097664);   // 131072 B
  _Float16*  p2l     = (_Float16*)(ws + 10228736);   // 131072 B -> 10359808
  _Float16*  ftH     = (_Float16*)(ws + 10359808);   // 33554432 B
  _Float16*  ftL     = (_Float16*)(ws + 43914240);   // 33554432 B -> 77468672

  const int use_ft = (ws_size >= 77468672ull) ? 1 : 0;
  const int npre = use_ft ? (197 + 4096) : 197;

  // blocks 0..31: FPS; 32..196: wsplit x4; 197..4292: feature transpose
  fused_pre_kernel<<<npre, 256, 0, stream>>>(xyz, new_xyz, features, ftH, ftL,
                                             w1, w2, w3, pw1, pw2, gma, var,
                                             pg, pv, w1h, w1l, w2h, w2l, w3h,
                                             w3l, p1h, p1l, p2h, p2l, bns);
  ballq_kernel<<<B_ * 16, 1024, 0, stream>>>(xyz, new_xyz, idxw);
  sa_kernel<<<B_ * 64, 512, 0, stream>>>(xyz, features, ftH, ftL, use_ft,
                                         w1h, w1l, w2h, w2l, w3h, w3l, bns,
                                         mu, bta, new_xyz, idxw, yb);
  phead_kernel<<<B_ * 16, 256, 0, stream>>>(yb, p1h, p1l, p2h, p2l, pw3, pb3,
                                            bns, pm, pb, new_xyz, msa, out);
}